// Round 8
// baseline (829.325 us; speedup 1.0000x reference)
//
#include <hip/hip_runtime.h>
#include <hip/hip_bf16.h>

#define NNODES 331776            // 81 * 4096
#define NGRAPH 4096
#define NBUCK  2048              // buckets
#define BNODES 162               // nodes per bucket (2048*162 == 331776)
#define TE     16384             // edges per tile
#define CAP    2560              // max edges/bucket (lambda=1953, 13.7 sigma)
#define MNODES 32                // nodes per wave in k_mlp2

// ---------------- deterministic bucket sort (no global atomics) ----------------

__global__ __launch_bounds__(256) void k_hist(const int* __restrict__ dst,
                                              int* __restrict__ H, int E) {
    __shared__ int h[NBUCK];
    int t = threadIdx.x, b = blockIdx.x;
    for (int i = t; i < NBUCK; i += 256) h[i] = 0;
    __syncthreads();
    int lo = b * TE, hi = min(E, lo + TE);
    for (int e = lo + t; e < hi; e += 256)
        atomicAdd(&h[dst[e] / BNODES], 1);
    __syncthreads();
    for (int i = t; i < NBUCK; i += 256) H[b * NBUCK + i] = h[i];
}

// per-bucket exclusive scan across tiles (in place); T[bin] = total
__global__ void k_colscan(int* __restrict__ H, int* __restrict__ T, int NT) {
    int bin = blockIdx.x * 256 + threadIdx.x;
    int s = 0;
    for (int t = 0; t < NT; t++) {
        int v = H[t * NBUCK + bin];
        H[t * NBUCK + bin] = s;
        s += v;
    }
    T[bin] = s;
}

// exclusive scan over the 2048 bucket totals -> Bstart[0..NBUCK]
__global__ __launch_bounds__(256) void k_binscan(const int* __restrict__ T,
                                                 int* __restrict__ Bstart) {
    __shared__ int tmp[256];
    int t = threadIdx.x;
    int base = t * 8;
    int loc[8]; int s = 0;
#pragma unroll
    for (int i = 0; i < 8; i++) { loc[i] = s; s += T[base + i]; }
    tmp[t] = s; __syncthreads();
    for (int o = 1; o < 256; o <<= 1) {
        int a = (t >= o) ? tmp[t - o] : 0;
        __syncthreads();
        tmp[t] += a;
        __syncthreads();
    }
    int excl = tmp[t] - s;
#pragma unroll
    for (int i = 0; i < 8; i++) Bstart[base + i] = excl + loc[i];
    if (t == 255) Bstart[NBUCK] = excl + s;
}

// place edges into bucket-major order; payload packs (src | dst_local<<19, esig)
// esig = sign(w)*exp(|w|) computed once here.
__global__ __launch_bounds__(256) void k_place(
    const int* __restrict__ src, const int* __restrict__ dst,
    const float* __restrict__ w,
    const int* __restrict__ H, const int* __restrict__ Bstart,
    int2* __restrict__ csrB, int E) {
    __shared__ int cur[NBUCK];
    int t = threadIdx.x, b = blockIdx.x;
    for (int i = t; i < NBUCK; i += 256)
        cur[i] = Bstart[i] + H[b * NBUCK + i];
    __syncthreads();
    int lo = b * TE, hi = min(E, lo + TE);
    for (int e = lo + t; e < hi; e += 256) {
        int d  = dst[e];
        int sx = src[e];
        float wv = w[e];
        float es = 0.f;
        if (wv > 0.f)      es = __expf(wv);
        else if (wv < 0.f) es = -__expf(-wv);
        int bin = d / BNODES;
        int dl  = d - bin * BNODES;
        int p = atomicAdd(&cur[bin], 1);        // LDS atomic; same-bin runs -> consecutive p
        int2 pk;
        pk.x = sx | (dl << 19);
        pk.y = __float_as_int(es);
        csrB[p] = pk;
    }
}

// per-bucket counting sort (in place), emits cnt[] and offs[] for free.
__global__ __launch_bounds__(256) void k_sortbucket(
    int2* __restrict__ csrB, const int* __restrict__ Bstart,
    int* __restrict__ cnt, int* __restrict__ offs) {
    __shared__ int2 pb[CAP];
    __shared__ int lcnt[BNODES];
    __shared__ int lpos[BNODES];
    int t = threadIdx.x, b = blockIdx.x;
    int lo = Bstart[b];
    int S  = Bstart[b + 1] - lo;
    if (S > CAP) S = CAP;                        // memory-safety guard (never expected)
    for (int i = t; i < BNODES; i += 256) lcnt[i] = 0;
    __syncthreads();
    for (int i = t; i < S; i += 256) {
        int2 pk = csrB[lo + i];                  // coalesced
        pb[i] = pk;
        atomicAdd(&lcnt[pk.x >> 19], 1);
    }
    __syncthreads();
    if (t == 0) {
        int s = 0;
        for (int i = 0; i < BNODES; i++) { lpos[i] = s; s += lcnt[i]; }
    }
    __syncthreads();
    int node0 = b * BNODES;
    for (int i = t; i < BNODES; i += 256) {
        cnt[node0 + i]  = lcnt[i];
        offs[node0 + i] = lo + lpos[i];
    }
    __syncthreads();
    for (int i = t; i < S; i += 256) {
        int2 pk = pb[i];
        int dl = pk.x >> 19;
        int p = atomicAdd(&lpos[dl], 1);
        int2 outv;
        outv.x = pk.x & 0x7FFFF;                 // unpacked src
        outv.y = pk.y;                           // esig
        csrB[lo + p] = outv;                     // bucket-local, L2-hot
    }
}

// ---------------- Layer 1 (h0 = deg, 1 feature -> 32) ----------------

__global__ __launch_bounds__(256) void k_layer1(
    const int* __restrict__ cnt, const int* __restrict__ offs,
    const int2* __restrict__ csr,
    float* __restrict__ spos, float* __restrict__ sneg,
    float* __restrict__ h1,
    const float* __restrict__ W1, const float* __restrict__ b1,
    const float* __restrict__ bias1,
    const float* __restrict__ c1s, const float* __restrict__ c1p,
    const float* __restrict__ c1n) {
    int t = threadIdx.x;
    int g = t >> 5, f = t & 31;
    int d = blockIdx.x * 8 + g;
    int beg = offs[d];
    int len = cnt[d];
    float sp = 0.f, sn = 0.f, up = 0.f, un = 0.f;
    for (int j = 0; j < len; j += 32) {
        int rem = len - j;
        if (f < rem) {
            int2 sw = csr[beg + j + f];            // coalesced 8B/lane
            float es = __int_as_float(sw.y);
            float degs = (float)cnt[sw.x];          // parallel gather, L2-hot
            float ep = fmaxf(es, 0.f), en = fmaxf(-es, 0.f);
            sp += ep; sn += en; up += degs * ep; un += degs * en;
        }
    }
    for (int m = 16; m; m >>= 1) {
        sp += __shfl_xor(sp, m, 32);
        sn += __shfl_xor(sn, m, 32);
        up += __shfl_xor(up, m, 32);
        un += __shfl_xor(un, m, 32);
    }
    if (f == 0) { spos[d] = sp; sneg[d] = sn; }
    float hp = up / fmaxf(sp, 1e-20f);
    float hn = un / fmaxf(sn, 1e-20f);
    float x0 = c1s[0] * (float)len;   // deg[d] == len
    float x1 = c1p[0] * hp;
    float x2 = c1n[0] * hn;
    float v = W1[f * 3] * x0 + W1[f * 3 + 1] * x1 + W1[f * 3 + 2] * x2
            + b1[f] + bias1[f];
    h1[d * 32 + f] = fmaxf(v, 0.f);                 // coalesced 128B/node
}

// ---------------- Layer-2 aggregation only (no LDS -> max occupancy) ----------
// Half-wave per node; 8-wide gather unroll keeps 8 L3 loads in flight.

__global__ __launch_bounds__(256) void k_agg(
    const int* __restrict__ cnt, const int* __restrict__ offs,
    const int2* __restrict__ csr,
    const float* __restrict__ spos, const float* __restrict__ sneg,
    const float* __restrict__ h1,
    float* __restrict__ hp, float* __restrict__ hn) {
    int t = threadIdx.x;
    int g = t >> 5, f = t & 31;
    int d = blockIdx.x * 8 + g;     // NNODES % 8 == 0
    int beg = offs[d];
    int len = cnt[d];
    float ap = 0.f, an = 0.f;
    for (int j = 0; j < len; j += 32) {
        int rem = len - j;
        int sx = 0;
        float es = 0.f;
        if (f < rem) {
            int2 sw = csr[beg + j + f];            // coalesced 8B/lane
            sx = sw.x;
            es = __int_as_float(sw.y);
        }
        int n = rem < 32 ? rem : 32;
        int q = 0;
        for (; q + 8 <= n; q += 8) {
            int   s0 = __shfl(sx, q,     32);
            int   s1 = __shfl(sx, q + 1, 32);
            int   s2 = __shfl(sx, q + 2, 32);
            int   s3 = __shfl(sx, q + 3, 32);
            int   s4 = __shfl(sx, q + 4, 32);
            int   s5 = __shfl(sx, q + 5, 32);
            int   s6 = __shfl(sx, q + 6, 32);
            int   s7 = __shfl(sx, q + 7, 32);
            float e0 = __shfl(es, q,     32);
            float e1 = __shfl(es, q + 1, 32);
            float e2 = __shfl(es, q + 2, 32);
            float e3 = __shfl(es, q + 3, 32);
            float e4 = __shfl(es, q + 4, 32);
            float e5 = __shfl(es, q + 5, 32);
            float e6 = __shfl(es, q + 6, 32);
            float e7 = __shfl(es, q + 7, 32);
            float h0 = h1[s0 * 32 + f];             // 8 independent gathers in flight
            float v1 = h1[s1 * 32 + f];
            float v2 = h1[s2 * 32 + f];
            float v3 = h1[s3 * 32 + f];
            float v4 = h1[s4 * 32 + f];
            float v5 = h1[s5 * 32 + f];
            float v6 = h1[s6 * 32 + f];
            float v7 = h1[s7 * 32 + f];
            ap += fmaxf(e0, 0.f) * h0; an += fmaxf(-e0, 0.f) * h0;
            ap += fmaxf(e1, 0.f) * v1; an += fmaxf(-e1, 0.f) * v1;
            ap += fmaxf(e2, 0.f) * v2; an += fmaxf(-e2, 0.f) * v2;
            ap += fmaxf(e3, 0.f) * v3; an += fmaxf(-e3, 0.f) * v3;
            ap += fmaxf(e4, 0.f) * v4; an += fmaxf(-e4, 0.f) * v4;
            ap += fmaxf(e5, 0.f) * v5; an += fmaxf(-e5, 0.f) * v5;
            ap += fmaxf(e6, 0.f) * v6; an += fmaxf(-e6, 0.f) * v6;
            ap += fmaxf(e7, 0.f) * v7; an += fmaxf(-e7, 0.f) * v7;
        }
        for (; q + 4 <= n; q += 4) {
            int   s0 = __shfl(sx, q,     32);
            int   s1 = __shfl(sx, q + 1, 32);
            int   s2 = __shfl(sx, q + 2, 32);
            int   s3 = __shfl(sx, q + 3, 32);
            float e0 = __shfl(es, q,     32);
            float e1 = __shfl(es, q + 1, 32);
            float e2 = __shfl(es, q + 2, 32);
            float e3 = __shfl(es, q + 3, 32);
            float h0 = h1[s0 * 32 + f];
            float v1 = h1[s1 * 32 + f];
            float v2 = h1[s2 * 32 + f];
            float v3 = h1[s3 * 32 + f];
            ap += fmaxf(e0, 0.f) * h0; an += fmaxf(-e0, 0.f) * h0;
            ap += fmaxf(e1, 0.f) * v1; an += fmaxf(-e1, 0.f) * v1;
            ap += fmaxf(e2, 0.f) * v2; an += fmaxf(-e2, 0.f) * v2;
            ap += fmaxf(e3, 0.f) * v3; an += fmaxf(-e3, 0.f) * v3;
        }
        for (; q < n; q++) {
            int   s0 = __shfl(sx, q, 32);
            float e0 = __shfl(es, q, 32);
            float h0 = h1[s0 * 32 + f];
            ap += fmaxf(e0, 0.f) * h0;
            an += fmaxf(-e0, 0.f) * h0;
        }
    }
    hp[d * 32 + f] = ap / fmaxf(spos[d], 1e-20f);
    hn[d * 32 + f] = an / fmaxf(sneg[d], 1e-20f);
}

// ---------------- Layer-2 MLP: wave-per-node-batch, weight-stationary --------
// Weights (scaled by c2s/c2p/c2n) live in 96 VGPRs per lane (f = lane&31; the
// upper half duplicates). Activations are WAVE-UNIFORM: node index is
// readfirstlane'd, so x loads become s_load broadcasts feeding v_fmac(v,s,v).
// h2 written IN PLACE over hn (node-partitioned; same-wave read-then-write).
// amdgpu_waves_per_eu(2,4): tell regalloc 4 waves/EU is fine -> keep 96-reg
// weight array resident instead of remat-reloading (the R5-R7 failure mode).

__global__ __attribute__((amdgpu_flat_work_group_size(256, 256),
                          amdgpu_waves_per_eu(2, 4)))
void k_mlp2(const float* __restrict__ h1, const float* __restrict__ hp,
            float* hnh2,                     // NOT restrict: read hn, write h2
            const float* __restrict__ W2, const float* __restrict__ b2,
            const float* __restrict__ bias2,
            const float* __restrict__ c2s, const float* __restrict__ c2p,
            const float* __restrict__ c2n) {
    int t = threadIdx.x;
    int lane = t & 63;
    int f = lane & 31;
    int half = lane >> 5;
    int wv = __builtin_amdgcn_readfirstlane(blockIdx.x * 4 + (t >> 6));
    int node0 = wv * MNODES;

    float c0 = c2s[0], c1 = c2p[0], c2v = c2n[0];
    // scaled weight row for output f: 96 VGPRs, loop-invariant across nodes
    float wreg[96];
    const float* wrow = W2 + f * 96;
#pragma unroll
    for (int j = 0; j < 32; j++) wreg[j]      = wrow[j]      * c0;
#pragma unroll
    for (int j = 0; j < 32; j++) wreg[32 + j] = wrow[32 + j] * c1;
#pragma unroll
    for (int j = 0; j < 32; j++) wreg[64 + j] = wrow[64 + j] * c2v;
    float bb = b2[f] + bias2[f];

#pragma unroll 1
    for (int n = 0; n < MNODES; n++) {
        size_t off = (size_t)(node0 + n) * 32;
        const float* x0 = h1   + off;       // wave-uniform -> s_load broadcast
        const float* x1 = hp   + off;
        const float* x2 = hnh2 + off;
        float acc = bb;
#pragma unroll
        for (int j = 0; j < 32; j++) acc = fmaf(wreg[j],      x0[j], acc);
#pragma unroll
        for (int j = 0; j < 32; j++) acc = fmaf(wreg[32 + j], x1[j], acc);
#pragma unroll
        for (int j = 0; j < 32; j++) acc = fmaf(wreg[64 + j], x2[j], acc);
        float h2v = fmaxf(acc, 0.f);
        if (half == 0) hnh2[off + f] = h2v;  // after x2 reads of same row
    }
}

// ---------------- conv1: y1[node,o] = bk1[o] + k1[o,:] . [h1row | h2row] -----
// Thread per (node, o): all-register, 32 float4 loads + 64 FMA.

__global__ __launch_bounds__(256) void k_conv1(
    const float* __restrict__ h1, const float* __restrict__ h2,
    const float* __restrict__ k1, const float* __restrict__ bk1,
    float* __restrict__ y1) {
    int idx = blockIdx.x * 256 + threadIdx.x;      // < NNODES*16
    int node = idx >> 4, o = idx & 15;
    const float4* z1 = (const float4*)(h1 + (size_t)node * 32);
    const float4* z2 = (const float4*)(h2 + (size_t)node * 32);
    const float4* ka = (const float4*)(k1 + o * 64);
    float acc = bk1[o];
#pragma unroll
    for (int k = 0; k < 8; k++) {
        float4 a = z1[k], w = ka[k];
        acc += w.x * a.x + w.y * a.y + w.z * a.z + w.w * a.w;
    }
#pragma unroll
    for (int k = 0; k < 8; k++) {
        float4 a = z2[k], w = ka[8 + k];
        acc += w.x * a.x + w.y * a.y + w.z * a.z + w.w * a.w;
    }
    y1[idx] = acc;
}

// ---------------- Wfc transpose (for coalesced FC reads) ----------------

__global__ void k_transpose(const float* __restrict__ Wfc, float* __restrict__ WfcT) {
    int i = blockIdx.x * 256 + threadIdx.x;
    if (i < 128 * 416) {
        int u = i / 416, c = i - u * 416;
        WfcT[c * 128 + u] = Wfc[i];
    }
}

// ---------------- Head: maxpool -> conv2 -> FC -> classifier -> log_softmax ----

__global__ __launch_bounds__(128) void k_head(
    const float* __restrict__ y1, const float* __restrict__ k2,
    const float* __restrict__ bk2, const float* __restrict__ WfcT,
    const float* __restrict__ bfc, const float* __restrict__ Wc,
    const float* __restrict__ bc, float* __restrict__ out) {
    __shared__ float yl[1296];       // 81 positions x 16 ch, [p][ch]
    __shared__ float zl[16][41];     // after maxpool, [ch][pos<40], pad
    __shared__ float xr[416];        // conv2 out, index oc*13+t
    __shared__ float k2s[1536];
    __shared__ float fl[128];
    __shared__ float ll[10];
    int t = threadIdx.x;
    int b = blockIdx.x;
    const float* yb = y1 + (size_t)b * 1296;
    for (int i = t; i < 1296; i += 128) yl[i] = yb[i];
    for (int i = t; i < 1536; i += 128) k2s[i] = k2[i];
    __syncthreads();
    // maxpool over position pairs (drop pos 80)
    for (int i = t; i < 640; i += 128) {
        int ic = i & 15, p = i >> 4;
        zl[ic][p] = fmaxf(yl[(2 * p) * 16 + ic], yl[(2 * p + 1) * 16 + ic]);
    }
    __syncthreads();
    // conv2: 32 out-ch x 13 positions, stride 3, k=3
    for (int i = t; i < 416; i += 128) {
        int oc = i / 13, tt = i - oc * 13;
        float acc = bk2[oc];
        for (int ic = 0; ic < 16; ic++) {
            const float* kk = &k2s[(oc * 16 + ic) * 3];
            acc += zl[ic][3 * tt]     * kk[0]
                 + zl[ic][3 * tt + 1] * kk[1]
                 + zl[ic][3 * tt + 2] * kk[2];
        }
        xr[i] = acc;
    }
    __syncthreads();
    // FC 416 -> 128, one thread per output, coalesced WfcT reads
    {
        float acc = bfc[t];
        for (int i = 0; i < 416; i++) acc += xr[i] * WfcT[i * 128 + t];
        fl[t] = fmaxf(acc, 0.f);
    }
    __syncthreads();
    if (t < 10) {
        float acc = bc[t];
        for (int u = 0; u < 128; u++) acc += fl[u] * Wc[t * 128 + u];
        ll[t] = acc;
    }
    __syncthreads();
    if (t < 10) {
        float m = -1e30f;
        for (int c = 0; c < 10; c++) m = fmaxf(m, ll[c]);
        float s = 0.f;
        for (int c = 0; c < 10; c++) s += __expf(ll[c] - m);
        out[b * 10 + t] = ll[t] - m - __logf(s);
    }
}

// ---------------- launch ----------------

extern "C" void kernel_launch(void* const* d_in, const int* in_sizes, int n_in,
                              void* d_out, int out_size, void* d_ws, size_t ws_size,
                              hipStream_t stream) {
    const int*   src   = (const int*)d_in[0];
    const int*   dst   = (const int*)d_in[1];
    const float* w     = (const float*)d_in[2];
    const float* W1    = (const float*)d_in[4];
    const float* b1    = (const float*)d_in[5];
    const float* bias1 = (const float*)d_in[6];
    const float* c1s   = (const float*)d_in[7];
    const float* c1p   = (const float*)d_in[8];
    const float* c1n   = (const float*)d_in[9];
    const float* W2    = (const float*)d_in[10];
    const float* b2    = (const float*)d_in[11];
    const float* bias2 = (const float*)d_in[12];
    const float* c2s   = (const float*)d_in[13];
    const float* c2p   = (const float*)d_in[14];
    const float* c2n   = (const float*)d_in[15];
    const float* k1    = (const float*)d_in[16];
    const float* bk1   = (const float*)d_in[17];
    const float* k2    = (const float*)d_in[18];
    const float* bk2   = (const float*)d_in[19];
    const float* Wfc   = (const float*)d_in[20];
    const float* bfc   = (const float*)d_in[21];
    const float* Wc    = (const float*)d_in[22];
    const float* bc    = (const float*)d_in[23];
    const int E = in_sizes[0];
    const int NT = (E + TE - 1) / TE;

    // workspace carve (256B aligned)
    size_t off = 0;
    auto carve = [&](size_t bytes) -> char* {
        char* p = (char*)d_ws + off;
        off = (off + bytes + 255) & ~(size_t)255;
        return p;
    };
    int*   cnt    = (int*)  carve((size_t)NNODES * 4);
    int*   offs   = (int*)  carve((size_t)NNODES * 4);
    int2*  csrB   = (int2*) carve((size_t)E * 8);
    int*   H      = (int*)  carve((size_t)NT * NBUCK * 4);
    int*   T      = (int*)  carve((size_t)NBUCK * 4);
    int*   Bstart = (int*)  carve((size_t)(NBUCK + 1) * 4);
    float* spos   = (float*)carve((size_t)NNODES * 4);
    float* sneg   = (float*)carve((size_t)NNODES * 4);
    float* h1     = (float*)carve((size_t)NNODES * 32 * 4);
    float* hp     = (float*)carve((size_t)NNODES * 32 * 4);
    float* hn     = (float*)carve((size_t)NNODES * 32 * 4);   // becomes h2 in-place
    float* y1     = (float*)carve((size_t)NNODES * 16 * 4);
    float* WfcT   = (float*)carve((size_t)128 * 416 * 4);
    (void)ws_size;

    k_hist      <<<NT, 256, 0, stream>>>(dst, H, E);
    k_colscan   <<<NBUCK / 256, 256, 0, stream>>>(H, T, NT);
    k_binscan   <<<1, 256, 0, stream>>>(T, Bstart);
    k_place     <<<NT, 256, 0, stream>>>(src, dst, w, H, Bstart, csrB, E);
    k_sortbucket<<<NBUCK, 256, 0, stream>>>(csrB, Bstart, cnt, offs);
    k_layer1    <<<NNODES / 8, 256, 0, stream>>>(cnt, offs, csrB, spos, sneg, h1,
                                                 W1, b1, bias1, c1s, c1p, c1n);
    k_transpose <<<(128 * 416 + 255) / 256, 256, 0, stream>>>(Wfc, WfcT);
    k_agg       <<<NNODES / 8, 256, 0, stream>>>(cnt, offs, csrB, spos, sneg, h1,
                                                 hp, hn);
    k_mlp2      <<<NNODES / (MNODES * 4), 256, 0, stream>>>(h1, hp, hn,
                                                            W2, b2, bias2,
                                                            c2s, c2p, c2n);
    k_conv1     <<<NNODES * 16 / 256, 256, 0, stream>>>(h1, hn, k1, bk1, y1);
    k_head      <<<NGRAPH, 128, 0, stream>>>(y1, k2, bk2, WfcT, bfc, Wc, bc,
                                             (float*)d_out);
}

// Round 9
// 640.779 us; speedup vs baseline: 1.2942x; 1.2942x over previous
//
#include <hip/hip_runtime.h>
#include <hip/hip_bf16.h>

#define NNODES 331776            // 81 * 4096
#define NGRAPH 4096
#define NBUCK  2048              // buckets
#define BNODES 162               // nodes per bucket (2048*162 == 331776)
#define TE     16384             // edges per tile
#define CAP    2560              // max edges/bucket (lambda=1953, 13.7 sigma)

// ---------------- deterministic bucket sort (no global atomics) ----------------

__global__ __launch_bounds__(256) void k_hist(const int* __restrict__ dst,
                                              int* __restrict__ H, int E) {
    __shared__ int h[NBUCK];
    int t = threadIdx.x, b = blockIdx.x;
    for (int i = t; i < NBUCK; i += 256) h[i] = 0;
    __syncthreads();
    int lo = b * TE, hi = min(E, lo + TE);
    for (int e = lo + t; e < hi; e += 256)
        atomicAdd(&h[dst[e] / BNODES], 1);
    __syncthreads();
    for (int i = t; i < NBUCK; i += 256) H[b * NBUCK + i] = h[i];
}

// per-bucket exclusive scan across tiles (in place); T[bin] = total
__global__ void k_colscan(int* __restrict__ H, int* __restrict__ T, int NT) {
    int bin = blockIdx.x * 256 + threadIdx.x;
    int s = 0;
    for (int t = 0; t < NT; t++) {
        int v = H[t * NBUCK + bin];
        H[t * NBUCK + bin] = s;
        s += v;
    }
    T[bin] = s;
}

// exclusive scan over the 2048 bucket totals -> Bstart[0..NBUCK]
__global__ __launch_bounds__(256) void k_binscan(const int* __restrict__ T,
                                                 int* __restrict__ Bstart) {
    __shared__ int tmp[256];
    int t = threadIdx.x;
    int base = t * 8;
    int loc[8]; int s = 0;
#pragma unroll
    for (int i = 0; i < 8; i++) { loc[i] = s; s += T[base + i]; }
    tmp[t] = s; __syncthreads();
    for (int o = 1; o < 256; o <<= 1) {
        int a = (t >= o) ? tmp[t - o] : 0;
        __syncthreads();
        tmp[t] += a;
        __syncthreads();
    }
    int excl = tmp[t] - s;
#pragma unroll
    for (int i = 0; i < 8; i++) Bstart[base + i] = excl + loc[i];
    if (t == 255) Bstart[NBUCK] = excl + s;
}

// place edges into bucket-major order; payload packs (src | dst_local<<19, esig)
// esig = sign(w)*exp(|w|) computed once here.
__global__ __launch_bounds__(256) void k_place(
    const int* __restrict__ src, const int* __restrict__ dst,
    const float* __restrict__ w,
    const int* __restrict__ H, const int* __restrict__ Bstart,
    int2* __restrict__ csrB, int E) {
    __shared__ int cur[NBUCK];
    int t = threadIdx.x, b = blockIdx.x;
    for (int i = t; i < NBUCK; i += 256)
        cur[i] = Bstart[i] + H[b * NBUCK + i];
    __syncthreads();
    int lo = b * TE, hi = min(E, lo + TE);
    for (int e = lo + t; e < hi; e += 256) {
        int d  = dst[e];
        int sx = src[e];
        float wv = w[e];
        float es = 0.f;
        if (wv > 0.f)      es = __expf(wv);
        else if (wv < 0.f) es = -__expf(-wv);
        int bin = d / BNODES;
        int dl  = d - bin * BNODES;
        int p = atomicAdd(&cur[bin], 1);        // LDS atomic; same-bin runs -> consecutive p
        int2 pk;
        pk.x = sx | (dl << 19);
        pk.y = __float_as_int(es);
        csrB[p] = pk;
    }
}

// per-bucket counting sort (in place), emits cnt[] and offs[] for free.
__global__ __launch_bounds__(256) void k_sortbucket(
    int2* __restrict__ csrB, const int* __restrict__ Bstart,
    int* __restrict__ cnt, int* __restrict__ offs) {
    __shared__ int2 pb[CAP];
    __shared__ int lcnt[BNODES];
    __shared__ int lpos[BNODES];
    int t = threadIdx.x, b = blockIdx.x;
    int lo = Bstart[b];
    int S  = Bstart[b + 1] - lo;
    if (S > CAP) S = CAP;                        // memory-safety guard (never expected)
    for (int i = t; i < BNODES; i += 256) lcnt[i] = 0;
    __syncthreads();
    for (int i = t; i < S; i += 256) {
        int2 pk = csrB[lo + i];                  // coalesced
        pb[i] = pk;
        atomicAdd(&lcnt[pk.x >> 19], 1);
    }
    __syncthreads();
    if (t == 0) {
        int s = 0;
        for (int i = 0; i < BNODES; i++) { lpos[i] = s; s += lcnt[i]; }
    }
    __syncthreads();
    int node0 = b * BNODES;
    for (int i = t; i < BNODES; i += 256) {
        cnt[node0 + i]  = lcnt[i];
        offs[node0 + i] = lo + lpos[i];
    }
    __syncthreads();
    for (int i = t; i < S; i += 256) {
        int2 pk = pb[i];
        int dl = pk.x >> 19;
        int p = atomicAdd(&lpos[dl], 1);
        int2 outv;
        outv.x = pk.x & 0x7FFFF;                 // unpacked src
        outv.y = pk.y;                           // esig
        csrB[lo + p] = outv;                     // bucket-local, L2-hot
    }
}

// ---------------- Layer 1 (h0 = deg, 1 feature -> 32) ----------------
// Also emits h1b (bf16 copy) so k_agg's random gathers move 2B/lane not 4B.

__global__ __launch_bounds__(256) void k_layer1(
    const int* __restrict__ cnt, const int* __restrict__ offs,
    const int2* __restrict__ csr,
    float* __restrict__ spos, float* __restrict__ sneg,
    float* __restrict__ h1, __hip_bfloat16* __restrict__ h1b,
    const float* __restrict__ W1, const float* __restrict__ b1,
    const float* __restrict__ bias1,
    const float* __restrict__ c1s, const float* __restrict__ c1p,
    const float* __restrict__ c1n) {
    int t = threadIdx.x;
    int g = t >> 5, f = t & 31;
    int d = blockIdx.x * 8 + g;
    int beg = offs[d];
    int len = cnt[d];
    float sp = 0.f, sn = 0.f, up = 0.f, un = 0.f;
    for (int j = 0; j < len; j += 32) {
        int rem = len - j;
        if (f < rem) {
            int2 sw = csr[beg + j + f];            // coalesced 8B/lane
            float es = __int_as_float(sw.y);
            float degs = (float)cnt[sw.x];          // parallel gather, L2-hot
            float ep = fmaxf(es, 0.f), en = fmaxf(-es, 0.f);
            sp += ep; sn += en; up += degs * ep; un += degs * en;
        }
    }
    for (int m = 16; m; m >>= 1) {
        sp += __shfl_xor(sp, m, 32);
        sn += __shfl_xor(sn, m, 32);
        up += __shfl_xor(up, m, 32);
        un += __shfl_xor(un, m, 32);
    }
    if (f == 0) { spos[d] = sp; sneg[d] = sn; }
    float hp = up / fmaxf(sp, 1e-20f);
    float hn = un / fmaxf(sn, 1e-20f);
    float x0 = c1s[0] * (float)len;   // deg[d] == len
    float x1 = c1p[0] * hp;
    float x2 = c1n[0] * hn;
    float v = W1[f * 3] * x0 + W1[f * 3 + 1] * x1 + W1[f * 3 + 2] * x2
            + b1[f] + bias1[f];
    v = fmaxf(v, 0.f);
    h1[d * 32 + f]  = v;                            // coalesced 128B/node
    h1b[d * 32 + f] = __float2bfloat16(v);          // bf16 gather table
}

// ---------------- Layer-2 aggregation only (no LDS -> max occupancy) ----------
// Half-wave per node; 8-wide gather unroll; gathers read the bf16 h1 table
// (64B/edge line traffic instead of 128B -> halves L3 gather bytes).

__global__ __launch_bounds__(256) void k_agg(
    const int* __restrict__ cnt, const int* __restrict__ offs,
    const int2* __restrict__ csr,
    const float* __restrict__ spos, const float* __restrict__ sneg,
    const __hip_bfloat16* __restrict__ h1b,
    float* __restrict__ hp, float* __restrict__ hn) {
    int t = threadIdx.x;
    int g = t >> 5, f = t & 31;
    int d = blockIdx.x * 8 + g;     // NNODES % 8 == 0
    int beg = offs[d];
    int len = cnt[d];
    float ap = 0.f, an = 0.f;
    for (int j = 0; j < len; j += 32) {
        int rem = len - j;
        int sx = 0;
        float es = 0.f;
        if (f < rem) {
            int2 sw = csr[beg + j + f];            // coalesced 8B/lane
            sx = sw.x;
            es = __int_as_float(sw.y);
        }
        int n = rem < 32 ? rem : 32;
        int q = 0;
        for (; q + 8 <= n; q += 8) {
            int   s0 = __shfl(sx, q,     32);
            int   s1 = __shfl(sx, q + 1, 32);
            int   s2 = __shfl(sx, q + 2, 32);
            int   s3 = __shfl(sx, q + 3, 32);
            int   s4 = __shfl(sx, q + 4, 32);
            int   s5 = __shfl(sx, q + 5, 32);
            int   s6 = __shfl(sx, q + 6, 32);
            int   s7 = __shfl(sx, q + 7, 32);
            float e0 = __shfl(es, q,     32);
            float e1 = __shfl(es, q + 1, 32);
            float e2 = __shfl(es, q + 2, 32);
            float e3 = __shfl(es, q + 3, 32);
            float e4 = __shfl(es, q + 4, 32);
            float e5 = __shfl(es, q + 5, 32);
            float e6 = __shfl(es, q + 6, 32);
            float e7 = __shfl(es, q + 7, 32);
            float h0 = __bfloat162float(h1b[s0 * 32 + f]);  // 8 gathers in flight
            float v1 = __bfloat162float(h1b[s1 * 32 + f]);
            float v2 = __bfloat162float(h1b[s2 * 32 + f]);
            float v3 = __bfloat162float(h1b[s3 * 32 + f]);
            float v4 = __bfloat162float(h1b[s4 * 32 + f]);
            float v5 = __bfloat162float(h1b[s5 * 32 + f]);
            float v6 = __bfloat162float(h1b[s6 * 32 + f]);
            float v7 = __bfloat162float(h1b[s7 * 32 + f]);
            ap += fmaxf(e0, 0.f) * h0; an += fmaxf(-e0, 0.f) * h0;
            ap += fmaxf(e1, 0.f) * v1; an += fmaxf(-e1, 0.f) * v1;
            ap += fmaxf(e2, 0.f) * v2; an += fmaxf(-e2, 0.f) * v2;
            ap += fmaxf(e3, 0.f) * v3; an += fmaxf(-e3, 0.f) * v3;
            ap += fmaxf(e4, 0.f) * v4; an += fmaxf(-e4, 0.f) * v4;
            ap += fmaxf(e5, 0.f) * v5; an += fmaxf(-e5, 0.f) * v5;
            ap += fmaxf(e6, 0.f) * v6; an += fmaxf(-e6, 0.f) * v6;
            ap += fmaxf(e7, 0.f) * v7; an += fmaxf(-e7, 0.f) * v7;
        }
        for (; q < n; q++) {
            int   s0 = __shfl(sx, q, 32);
            float e0 = __shfl(es, q, 32);
            float h0 = __bfloat162float(h1b[s0 * 32 + f]);
            ap += fmaxf(e0, 0.f) * h0;
            an += fmaxf(-e0, 0.f) * h0;
        }
    }
    hp[d * 32 + f] = ap / fmaxf(spos[d], 1e-20f);
    hn[d * 32 + f] = an / fmaxf(sneg[d], 1e-20f);
}

// ---------------- Layer-2 MLP + fused conv1, one THREAD per node -------------
// THREE sequential passes (h1, hp, hn) so peak live set is ~70 floats:
// acc[32] + one 32-float row. W2/k1 via uniform (scalar) loads -> SGPR/K$.
// (Proven form: 106us, VGPR 52. Splitting conv1 out regressed to 185us - R8.)

__global__ __launch_bounds__(256, 2) void k_mlp(
    const float* __restrict__ h1, const float* __restrict__ hp,
    const float* __restrict__ hn,
    const float* __restrict__ W2, const float* __restrict__ b2,
    const float* __restrict__ bias2,
    const float* __restrict__ c2s, const float* __restrict__ c2p,
    const float* __restrict__ c2n,
    const float* __restrict__ k1, const float* __restrict__ bk1,
    float* __restrict__ y1) {
    int d = blockIdx.x * 256 + threadIdx.x;
    float acc[32];
#pragma unroll
    for (int f = 0; f < 32; f++) acc[f] = b2[f] + bias2[f];

#pragma unroll 1
    for (int p = 0; p < 3; p++) {                  // sequential: bounds liveness
        const float* base = (p == 0) ? h1 : ((p == 1) ? hp : hn);
        float sc = (p == 0) ? c2s[0] : ((p == 1) ? c2p[0] : c2n[0]);
        const float4* xv = (const float4*)(base + (size_t)d * 32);
        float4 X[8];
#pragma unroll
        for (int i = 0; i < 8; i++) X[i] = xv[i];
        const float* wb = W2 + p * 32;             // third of each W2 row
#pragma unroll
        for (int f = 0; f < 32; f++) {
            const float* wr = wb + f * 96;         // uniform -> s_load
            float s = 0.f;
#pragma unroll
            for (int k = 0; k < 8; k++) {
                float4 x = X[k];
                s += wr[4 * k]     * x.x + wr[4 * k + 1] * x.y
                   + wr[4 * k + 2] * x.z + wr[4 * k + 3] * x.w;
            }
            acc[f] += sc * s;
        }
    }
#pragma unroll
    for (int f = 0; f < 32; f++) acc[f] = fmaxf(acc[f], 0.f);   // h2

    float y[16];
    // conv1 second half: y[o] = bk1[o] + sum_f k1[o*64+32+f] * h2[f]
#pragma unroll
    for (int o = 0; o < 16; o++) {
        const float* kr = k1 + o * 64 + 32;
        float s = bk1[o];
#pragma unroll
        for (int f = 0; f < 32; f++) s += kr[f] * acc[f];
        y[o] = s;
    }
    // conv1 first half: reload h1 row (L1-hot) after acc is dead
    {
        const float4* av = (const float4*)(h1 + (size_t)d * 32);
        float4 A[8];
#pragma unroll
        for (int i = 0; i < 8; i++) A[i] = av[i];
#pragma unroll
        for (int o = 0; o < 16; o++) {
            const float* kr = k1 + o * 64;
            float s = 0.f;
#pragma unroll
            for (int k = 0; k < 8; k++) {
                float4 a = A[k];
                s += kr[4 * k]     * a.x + kr[4 * k + 1] * a.y
                   + kr[4 * k + 2] * a.z + kr[4 * k + 3] * a.w;
            }
            y[o] += s;
        }
    }
    float4* yo = (float4*)(y1 + (size_t)d * 16);
#pragma unroll
    for (int q = 0; q < 4; q++) {
        float4 v;
        v.x = y[4 * q]; v.y = y[4 * q + 1]; v.z = y[4 * q + 2]; v.w = y[4 * q + 3];
        yo[q] = v;
    }
}

// ---------------- Wfc transpose (for coalesced FC reads) ----------------

__global__ void k_transpose(const float* __restrict__ Wfc, float* __restrict__ WfcT) {
    int i = blockIdx.x * 256 + threadIdx.x;
    if (i < 128 * 416) {
        int u = i / 416, c = i - u * 416;
        WfcT[c * 128 + u] = Wfc[i];
    }
}

// ---------------- Head: maxpool -> conv2 -> FC -> classifier -> log_softmax ----

__global__ __launch_bounds__(128) void k_head(
    const float* __restrict__ y1, const float* __restrict__ k2,
    const float* __restrict__ bk2, const float* __restrict__ WfcT,
    const float* __restrict__ bfc, const float* __restrict__ Wc,
    const float* __restrict__ bc, float* __restrict__ out) {
    __shared__ float yl[1296];       // 81 positions x 16 ch, [p][ch]
    __shared__ float zl[16][41];     // after maxpool, [ch][pos<40], pad
    __shared__ float xr[416];        // conv2 out, index oc*13+t
    __shared__ float k2s[1536];
    __shared__ float fl[128];
    __shared__ float ll[10];
    int t = threadIdx.x;
    int b = blockIdx.x;
    const float* yb = y1 + (size_t)b * 1296;
    for (int i = t; i < 1296; i += 128) yl[i] = yb[i];
    for (int i = t; i < 1536; i += 128) k2s[i] = k2[i];
    __syncthreads();
    // maxpool over position pairs (drop pos 80)
    for (int i = t; i < 640; i += 128) {
        int ic = i & 15, p = i >> 4;
        zl[ic][p] = fmaxf(yl[(2 * p) * 16 + ic], yl[(2 * p + 1) * 16 + ic]);
    }
    __syncthreads();
    // conv2: 32 out-ch x 13 positions, stride 3, k=3
    for (int i = t; i < 416; i += 128) {
        int oc = i / 13, tt = i - oc * 13;
        float acc = bk2[oc];
        for (int ic = 0; ic < 16; ic++) {
            const float* kk = &k2s[(oc * 16 + ic) * 3];
            acc += zl[ic][3 * tt]     * kk[0]
                 + zl[ic][3 * tt + 1] * kk[1]
                 + zl[ic][3 * tt + 2] * kk[2];
        }
        xr[i] = acc;
    }
    __syncthreads();
    // FC 416 -> 128, one thread per output, coalesced WfcT reads
    {
        float acc = bfc[t];
        for (int i = 0; i < 416; i++) acc += xr[i] * WfcT[i * 128 + t];
        fl[t] = fmaxf(acc, 0.f);
    }
    __syncthreads();
    if (t < 10) {
        float acc = bc[t];
        for (int u = 0; u < 128; u++) acc += fl[u] * Wc[t * 128 + u];
        ll[t] = acc;
    }
    __syncthreads();
    if (t < 10) {
        float m = -1e30f;
        for (int c = 0; c < 10; c++) m = fmaxf(m, ll[c]);
        float s = 0.f;
        for (int c = 0; c < 10; c++) s += __expf(ll[c] - m);
        out[b * 10 + t] = ll[t] - m - __logf(s);
    }
}

// ---------------- launch ----------------

extern "C" void kernel_launch(void* const* d_in, const int* in_sizes, int n_in,
                              void* d_out, int out_size, void* d_ws, size_t ws_size,
                              hipStream_t stream) {
    const int*   src   = (const int*)d_in[0];
    const int*   dst   = (const int*)d_in[1];
    const float* w     = (const float*)d_in[2];
    const float* W1    = (const float*)d_in[4];
    const float* b1    = (const float*)d_in[5];
    const float* bias1 = (const float*)d_in[6];
    const float* c1s   = (const float*)d_in[7];
    const float* c1p   = (const float*)d_in[8];
    const float* c1n   = (const float*)d_in[9];
    const float* W2    = (const float*)d_in[10];
    const float* b2    = (const float*)d_in[11];
    const float* bias2 = (const float*)d_in[12];
    const float* c2s   = (const float*)d_in[13];
    const float* c2p   = (const float*)d_in[14];
    const float* c2n   = (const float*)d_in[15];
    const float* k1    = (const float*)d_in[16];
    const float* bk1   = (const float*)d_in[17];
    const float* k2    = (const float*)d_in[18];
    const float* bk2   = (const float*)d_in[19];
    const float* Wfc   = (const float*)d_in[20];
    const float* bfc   = (const float*)d_in[21];
    const float* Wc    = (const float*)d_in[22];
    const float* bc    = (const float*)d_in[23];
    const int E = in_sizes[0];
    const int NT = (E + TE - 1) / TE;

    // workspace carve (256B aligned)
    size_t off = 0;
    auto carve = [&](size_t bytes) -> char* {
        char* p = (char*)d_ws + off;
        off = (off + bytes + 255) & ~(size_t)255;
        return p;
    };
    int*   cnt    = (int*)  carve((size_t)NNODES * 4);
    int*   offs   = (int*)  carve((size_t)NNODES * 4);
    int2*  csrB   = (int2*) carve((size_t)E * 8);
    int*   H      = (int*)  carve((size_t)NT * NBUCK * 4);
    int*   T      = (int*)  carve((size_t)NBUCK * 4);
    int*   Bstart = (int*)  carve((size_t)(NBUCK + 1) * 4);
    float* spos   = (float*)carve((size_t)NNODES * 4);
    float* sneg   = (float*)carve((size_t)NNODES * 4);
    float* h1     = (float*)carve((size_t)NNODES * 32 * 4);
    __hip_bfloat16* h1b = (__hip_bfloat16*)carve((size_t)NNODES * 32 * 2);
    float* hp     = (float*)carve((size_t)NNODES * 32 * 4);
    float* hn     = (float*)carve((size_t)NNODES * 32 * 4);
    float* y1     = (float*)carve((size_t)NNODES * 16 * 4);
    float* WfcT   = (float*)carve((size_t)128 * 416 * 4);
    (void)ws_size;

    k_hist      <<<NT, 256, 0, stream>>>(dst, H, E);
    k_colscan   <<<NBUCK / 256, 256, 0, stream>>>(H, T, NT);
    k_binscan   <<<1, 256, 0, stream>>>(T, Bstart);
    k_place     <<<NT, 256, 0, stream>>>(src, dst, w, H, Bstart, csrB, E);
    k_sortbucket<<<NBUCK, 256, 0, stream>>>(csrB, Bstart, cnt, offs);
    k_layer1    <<<NNODES / 8, 256, 0, stream>>>(cnt, offs, csrB, spos, sneg,
                                                 h1, h1b,
                                                 W1, b1, bias1, c1s, c1p, c1n);
    k_transpose <<<(128 * 416 + 255) / 256, 256, 0, stream>>>(Wfc, WfcT);
    k_agg       <<<NNODES / 8, 256, 0, stream>>>(cnt, offs, csrB, spos, sneg,
                                                 h1b, hp, hn);
    k_mlp       <<<NNODES / 256, 256, 0, stream>>>(h1, hp, hn, W2, b2, bias2,
                                                   c2s, c2p, c2n, k1, bk1, y1);
    k_head      <<<NGRAPH, 128, 0, stream>>>(y1, k2, bk2, WfcT, bfc, Wc, bc,
                                             (float*)d_out);
}

// Round 10
// 560.068 us; speedup vs baseline: 1.4808x; 1.1441x over previous
//
#include <hip/hip_runtime.h>
#include <hip/hip_bf16.h>

#define NNODES 331776            // 81 * 4096
#define NGRAPH 4096
#define NBUCK  2048              // buckets
#define BNODES 162               // nodes per bucket (2048*162 == 331776)
#define TE     16384             // edges per tile
#define CAP    2560              // max edges/bucket (lambda=1953, 13.7 sigma)

typedef __attribute__((ext_vector_type(8))) short bf8;   // 8 bf16 (4 VGPR)
typedef __attribute__((ext_vector_type(4))) float f4;    // 4 fp32 acc

static __device__ __forceinline__ short f2bf(float x) {
    return (short)__builtin_bit_cast(unsigned short, __float2bfloat16(x));
}

// ---------------- deterministic bucket sort (no global atomics) ----------------

__global__ __launch_bounds__(256) void k_hist(const int* __restrict__ dst,
                                              int* __restrict__ H, int E) {
    __shared__ int h[NBUCK];
    int t = threadIdx.x, b = blockIdx.x;
    for (int i = t; i < NBUCK; i += 256) h[i] = 0;
    __syncthreads();
    int lo = b * TE, hi = min(E, lo + TE);
    for (int e = lo + t; e < hi; e += 256)
        atomicAdd(&h[dst[e] / BNODES], 1);
    __syncthreads();
    for (int i = t; i < NBUCK; i += 256) H[b * NBUCK + i] = h[i];
}

// per-bucket exclusive scan across tiles (in place); T[bin] = total
__global__ void k_colscan(int* __restrict__ H, int* __restrict__ T, int NT) {
    int bin = blockIdx.x * 256 + threadIdx.x;
    int s = 0;
    for (int t = 0; t < NT; t++) {
        int v = H[t * NBUCK + bin];
        H[t * NBUCK + bin] = s;
        s += v;
    }
    T[bin] = s;
}

// exclusive scan over the 2048 bucket totals -> Bstart[0..NBUCK]
__global__ __launch_bounds__(256) void k_binscan(const int* __restrict__ T,
                                                 int* __restrict__ Bstart) {
    __shared__ int tmp[256];
    int t = threadIdx.x;
    int base = t * 8;
    int loc[8]; int s = 0;
#pragma unroll
    for (int i = 0; i < 8; i++) { loc[i] = s; s += T[base + i]; }
    tmp[t] = s; __syncthreads();
    for (int o = 1; o < 256; o <<= 1) {
        int a = (t >= o) ? tmp[t - o] : 0;
        __syncthreads();
        tmp[t] += a;
        __syncthreads();
    }
    int excl = tmp[t] - s;
#pragma unroll
    for (int i = 0; i < 8; i++) Bstart[base + i] = excl + loc[i];
    if (t == 255) Bstart[NBUCK] = excl + s;
}

// place edges into bucket-major order; payload packs (src | dst_local<<19, esig)
// esig = sign(w)*exp(|w|) computed once here.
__global__ __launch_bounds__(256) void k_place(
    const int* __restrict__ src, const int* __restrict__ dst,
    const float* __restrict__ w,
    const int* __restrict__ H, const int* __restrict__ Bstart,
    int2* __restrict__ csrB, int E) {
    __shared__ int cur[NBUCK];
    int t = threadIdx.x, b = blockIdx.x;
    for (int i = t; i < NBUCK; i += 256)
        cur[i] = Bstart[i] + H[b * NBUCK + i];
    __syncthreads();
    int lo = b * TE, hi = min(E, lo + TE);
    for (int e = lo + t; e < hi; e += 256) {
        int d  = dst[e];
        int sx = src[e];
        float wv = w[e];
        float es = 0.f;
        if (wv > 0.f)      es = __expf(wv);
        else if (wv < 0.f) es = -__expf(-wv);
        int bin = d / BNODES;
        int dl  = d - bin * BNODES;
        int p = atomicAdd(&cur[bin], 1);        // LDS atomic; same-bin runs -> consecutive p
        int2 pk;
        pk.x = sx | (dl << 19);
        pk.y = __float_as_int(es);
        csrB[p] = pk;
    }
}

// per-bucket counting sort (in place), emits cnt[] and offs[] for free.
__global__ __launch_bounds__(256) void k_sortbucket(
    int2* __restrict__ csrB, const int* __restrict__ Bstart,
    int* __restrict__ cnt, int* __restrict__ offs) {
    __shared__ int2 pb[CAP];
    __shared__ int lcnt[BNODES];
    __shared__ int lpos[BNODES];
    int t = threadIdx.x, b = blockIdx.x;
    int lo = Bstart[b];
    int S  = Bstart[b + 1] - lo;
    if (S > CAP) S = CAP;                        // memory-safety guard (never expected)
    for (int i = t; i < BNODES; i += 256) lcnt[i] = 0;
    __syncthreads();
    for (int i = t; i < S; i += 256) {
        int2 pk = csrB[lo + i];                  // coalesced
        pb[i] = pk;
        atomicAdd(&lcnt[pk.x >> 19], 1);
    }
    __syncthreads();
    if (t == 0) {
        int s = 0;
        for (int i = 0; i < BNODES; i++) { lpos[i] = s; s += lcnt[i]; }
    }
    __syncthreads();
    int node0 = b * BNODES;
    for (int i = t; i < BNODES; i += 256) {
        cnt[node0 + i]  = lcnt[i];
        offs[node0 + i] = lo + lpos[i];
    }
    __syncthreads();
    for (int i = t; i < S; i += 256) {
        int2 pk = pb[i];
        int dl = pk.x >> 19;
        int p = atomicAdd(&lpos[dl], 1);
        int2 outv;
        outv.x = pk.x & 0x7FFFF;                 // unpacked src
        outv.y = pk.y;                           // esig
        csrB[lo + p] = outv;                     // bucket-local, L2-hot
    }
}

// ---------------- Layer 1 (h0 = deg, 1 feature -> 32), bf16 output ----------

__global__ __launch_bounds__(256) void k_layer1(
    const int* __restrict__ cnt, const int* __restrict__ offs,
    const int2* __restrict__ csr,
    float* __restrict__ spos, float* __restrict__ sneg,
    unsigned short* __restrict__ h1b,
    const float* __restrict__ W1, const float* __restrict__ b1,
    const float* __restrict__ bias1,
    const float* __restrict__ c1s, const float* __restrict__ c1p,
    const float* __restrict__ c1n) {
    int t = threadIdx.x;
    int g = t >> 5, f = t & 31;
    int d = blockIdx.x * 8 + g;
    int beg = offs[d];
    int len = cnt[d];
    float sp = 0.f, sn = 0.f, up = 0.f, un = 0.f;
    for (int j = 0; j < len; j += 32) {
        int rem = len - j;
        if (f < rem) {
            int2 sw = csr[beg + j + f];            // coalesced 8B/lane
            float es = __int_as_float(sw.y);
            float degs = (float)cnt[sw.x];          // parallel gather, L2-hot
            float ep = fmaxf(es, 0.f), en = fmaxf(-es, 0.f);
            sp += ep; sn += en; up += degs * ep; un += degs * en;
        }
    }
    for (int m = 16; m; m >>= 1) {
        sp += __shfl_xor(sp, m, 32);
        sn += __shfl_xor(sn, m, 32);
        up += __shfl_xor(up, m, 32);
        un += __shfl_xor(un, m, 32);
    }
    if (f == 0) { spos[d] = sp; sneg[d] = sn; }
    float hp = up / fmaxf(sp, 1e-20f);
    float hn = un / fmaxf(sn, 1e-20f);
    float x0 = c1s[0] * (float)len;   // deg[d] == len
    float x1 = c1p[0] * hp;
    float x2 = c1n[0] * hn;
    float v = W1[f * 3] * x0 + W1[f * 3 + 1] * x1 + W1[f * 3 + 2] * x2
            + b1[f] + bias1[f];
    v = fmaxf(v, 0.f);
    h1b[d * 32 + f] = (unsigned short)f2bf(v);      // bf16 table (gathered + MFMA A)
}

// ---------------- Layer-2 aggregation only (no LDS -> max occupancy) ----------
// Half-wave per node; 8-wide gather unroll; gathers read the bf16 h1 table.

__global__ __launch_bounds__(256) void k_agg(
    const int* __restrict__ cnt, const int* __restrict__ offs,
    const int2* __restrict__ csr,
    const float* __restrict__ spos, const float* __restrict__ sneg,
    const unsigned short* __restrict__ h1b,
    float* __restrict__ hp, float* __restrict__ hn) {
    int t = threadIdx.x;
    int g = t >> 5, f = t & 31;
    int d = blockIdx.x * 8 + g;     // NNODES % 8 == 0
    int beg = offs[d];
    int len = cnt[d];
    float ap = 0.f, an = 0.f;
    for (int j = 0; j < len; j += 32) {
        int rem = len - j;
        int sx = 0;
        float es = 0.f;
        if (f < rem) {
            int2 sw = csr[beg + j + f];            // coalesced 8B/lane
            sx = sw.x;
            es = __int_as_float(sw.y);
        }
        int n = rem < 32 ? rem : 32;
        int q = 0;
        for (; q + 8 <= n; q += 8) {
            int   s0 = __shfl(sx, q,     32);
            int   s1 = __shfl(sx, q + 1, 32);
            int   s2 = __shfl(sx, q + 2, 32);
            int   s3 = __shfl(sx, q + 3, 32);
            int   s4 = __shfl(sx, q + 4, 32);
            int   s5 = __shfl(sx, q + 5, 32);
            int   s6 = __shfl(sx, q + 6, 32);
            int   s7 = __shfl(sx, q + 7, 32);
            float e0 = __shfl(es, q,     32);
            float e1 = __shfl(es, q + 1, 32);
            float e2 = __shfl(es, q + 2, 32);
            float e3 = __shfl(es, q + 3, 32);
            float e4 = __shfl(es, q + 4, 32);
            float e5 = __shfl(es, q + 5, 32);
            float e6 = __shfl(es, q + 6, 32);
            float e7 = __shfl(es, q + 7, 32);
            float h0 = __bfloat162float(__hip_bfloat16_raw{h1b[s0 * 32 + f]});
            float v1 = __bfloat162float(__hip_bfloat16_raw{h1b[s1 * 32 + f]});
            float v2 = __bfloat162float(__hip_bfloat16_raw{h1b[s2 * 32 + f]});
            float v3 = __bfloat162float(__hip_bfloat16_raw{h1b[s3 * 32 + f]});
            float v4 = __bfloat162float(__hip_bfloat16_raw{h1b[s4 * 32 + f]});
            float v5 = __bfloat162float(__hip_bfloat16_raw{h1b[s5 * 32 + f]});
            float v6 = __bfloat162float(__hip_bfloat16_raw{h1b[s6 * 32 + f]});
            float v7 = __bfloat162float(__hip_bfloat16_raw{h1b[s7 * 32 + f]});
            ap += fmaxf(e0, 0.f) * h0; an += fmaxf(-e0, 0.f) * h0;
            ap += fmaxf(e1, 0.f) * v1; an += fmaxf(-e1, 0.f) * v1;
            ap += fmaxf(e2, 0.f) * v2; an += fmaxf(-e2, 0.f) * v2;
            ap += fmaxf(e3, 0.f) * v3; an += fmaxf(-e3, 0.f) * v3;
            ap += fmaxf(e4, 0.f) * v4; an += fmaxf(-e4, 0.f) * v4;
            ap += fmaxf(e5, 0.f) * v5; an += fmaxf(-e5, 0.f) * v5;
            ap += fmaxf(e6, 0.f) * v6; an += fmaxf(-e6, 0.f) * v6;
            ap += fmaxf(e7, 0.f) * v7; an += fmaxf(-e7, 0.f) * v7;
        }
        for (; q < n; q++) {
            int   s0 = __shfl(sx, q, 32);
            float e0 = __shfl(es, q, 32);
            float h0 = __bfloat162float(__hip_bfloat16_raw{h1b[s0 * 32 + f]});
            ap += fmaxf(e0, 0.f) * h0;
            an += fmaxf(-e0, 0.f) * h0;
        }
    }
    hp[d * 32 + f] = ap / fmaxf(spos[d], 1e-20f);
    hn[d * 32 + f] = an / fmaxf(sneg[d], 1e-20f);
}

// ---------------- weight prep: bf16 transposed, scales folded ---------------
// W2sT[k][n] = bf16(W2[n][k] * c_{k/32})   (96 x 32)
// k1T[k][o]  = bf16(k1[o][k])              (64 x 16)

__global__ __launch_bounds__(256) void k_prep(
    const float* __restrict__ W2, const float* __restrict__ c2s,
    const float* __restrict__ c2p, const float* __restrict__ c2n,
    const float* __restrict__ k1,
    unsigned short* __restrict__ W2sT, unsigned short* __restrict__ k1T) {
    int i = blockIdx.x * 256 + threadIdx.x;
    if (i < 96 * 32) {
        int k = i >> 5, n = i & 31;
        float sc = (k < 32) ? c2s[0] : ((k < 64) ? c2p[0] : c2n[0]);
        W2sT[i] = (unsigned short)f2bf(W2[n * 96 + k] * sc);
    } else if (i < 96 * 32 + 64 * 16) {
        int j = i - 3072;
        int k = j >> 4, o = j & 15;
        k1T[j] = (unsigned short)f2bf(k1[o * 64 + k]);
    }
}

// ---------------- Layer-2 MLP + conv1 via MFMA ------------------------------
// Per wave-group of 16 nodes:
//   GEMM1: H2(16x32) = X(16x96) . W2sT(96x32)   -> 6 mfma_f32_16x16x32_bf16
//   relu + bias, transpose C->A layout via private LDS tile (bf16)
//   GEMM2: Y(16x16)  = [h1|h2](16x64) . k1T(64x16) -> 2 mfma
// Layouts (verified): A[m=lane&15][k=quad*8+j]; B[k=quad*8+j][n=lane&15];
// C/D[row=quad*4+reg][col=lane&15].

__global__ __launch_bounds__(256) void k_mlp_mfma(
    const unsigned short* __restrict__ h1b,
    const float* __restrict__ hp, const float* __restrict__ hn,
    const unsigned short* __restrict__ W2sT, const unsigned short* __restrict__ k1T,
    const float* __restrict__ b2, const float* __restrict__ bias2,
    const float* __restrict__ bk1,
    float* __restrict__ y1) {
    __shared__ unsigned short h2s[4][16 * 32];     // per-wave transpose tile
    int t = threadIdx.x;
    int wv = t >> 6;
    int lane = t & 63;
    int col = lane & 15;
    int quad = lane >> 4;

    float bv0 = b2[col] + bias2[col];
    float bv1 = b2[col + 16] + bias2[col + 16];
    float bky = bk1[col];

    // B-frags: W2sT (6) + k1T (2), loop-invariant, ~32 VGPR
    bf8 BW[2][3];
#pragma unroll
    for (int nt = 0; nt < 2; nt++)
#pragma unroll
        for (int kt = 0; kt < 3; kt++) {
            bf8 b;
#pragma unroll
            for (int j = 0; j < 8; j++)
                b[j] = (short)W2sT[(kt * 32 + quad * 8 + j) * 32 + nt * 16 + col];
            BW[nt][kt] = b;
        }
    bf8 BK[2];
#pragma unroll
    for (int kt = 0; kt < 2; kt++) {
        bf8 b;
#pragma unroll
        for (int j = 0; j < 8; j++)
            b[j] = (short)k1T[(kt * 32 + quad * 8 + j) * 16 + col];
        BK[kt] = b;
    }
    unsigned short* myT = h2s[wv];

#pragma unroll 1
    for (int g = 0; g < 4; g++) {
        int nbase = blockIdx.x * 256 + wv * 64 + g * 16;
        int node = nbase + col;                     // A-operand row m = col
        // A-frags
        bf8 a0 = *(const bf8*)(h1b + (size_t)node * 32 + quad * 8);
        const float4* php = (const float4*)(hp + (size_t)node * 32 + quad * 8);
        float4 p0 = php[0], p1 = php[1];
        const float4* phn = (const float4*)(hn + (size_t)node * 32 + quad * 8);
        float4 n0 = phn[0], n1 = phn[1];
        bf8 a1, a2;
        a1[0] = f2bf(p0.x); a1[1] = f2bf(p0.y); a1[2] = f2bf(p0.z); a1[3] = f2bf(p0.w);
        a1[4] = f2bf(p1.x); a1[5] = f2bf(p1.y); a1[6] = f2bf(p1.z); a1[7] = f2bf(p1.w);
        a2[0] = f2bf(n0.x); a2[1] = f2bf(n0.y); a2[2] = f2bf(n0.z); a2[3] = f2bf(n0.w);
        a2[4] = f2bf(n1.x); a2[5] = f2bf(n1.y); a2[6] = f2bf(n1.z); a2[7] = f2bf(n1.w);

        f4 acc0 = {bv0, bv0, bv0, bv0};
        f4 acc1 = {bv1, bv1, bv1, bv1};
        acc0 = __builtin_amdgcn_mfma_f32_16x16x32_bf16(a0, BW[0][0], acc0, 0, 0, 0);
        acc0 = __builtin_amdgcn_mfma_f32_16x16x32_bf16(a1, BW[0][1], acc0, 0, 0, 0);
        acc0 = __builtin_amdgcn_mfma_f32_16x16x32_bf16(a2, BW[0][2], acc0, 0, 0, 0);
        acc1 = __builtin_amdgcn_mfma_f32_16x16x32_bf16(a0, BW[1][0], acc1, 0, 0, 0);
        acc1 = __builtin_amdgcn_mfma_f32_16x16x32_bf16(a1, BW[1][1], acc1, 0, 0, 0);
        acc1 = __builtin_amdgcn_mfma_f32_16x16x32_bf16(a2, BW[1][2], acc1, 0, 0, 0);

        // relu -> bf16 -> LDS (C layout: row=quad*4+i, col)
#pragma unroll
        for (int i = 0; i < 4; i++) {
            int r = quad * 4 + i;
            myT[r * 32 + col]      = (unsigned short)f2bf(fmaxf(acc0[i], 0.f));
            myT[r * 32 + col + 16] = (unsigned short)f2bf(fmaxf(acc1[i], 0.f));
        }
        // read back in A layout (same wave -> compiler inserts lgkm wait)
        bf8 ah2 = *(const bf8*)(myT + col * 32 + quad * 8);

        f4 accy = {bky, bky, bky, bky};
        accy = __builtin_amdgcn_mfma_f32_16x16x32_bf16(a0,  BK[0], accy, 0, 0, 0);
        accy = __builtin_amdgcn_mfma_f32_16x16x32_bf16(ah2, BK[1], accy, 0, 0, 0);
#pragma unroll
        for (int i = 0; i < 4; i++)
            y1[(size_t)(nbase + quad * 4 + i) * 16 + col] = accy[i];
    }
}

// ---------------- Wfc transpose (for coalesced FC reads) ----------------

__global__ void k_transpose(const float* __restrict__ Wfc, float* __restrict__ WfcT) {
    int i = blockIdx.x * 256 + threadIdx.x;
    if (i < 128 * 416) {
        int u = i / 416, c = i - u * 416;
        WfcT[c * 128 + u] = Wfc[i];
    }
}

// ---------------- Head: maxpool -> conv2 -> FC -> classifier -> log_softmax ----

__global__ __launch_bounds__(128) void k_head(
    const float* __restrict__ y1, const float* __restrict__ k2,
    const float* __restrict__ bk2, const float* __restrict__ WfcT,
    const float* __restrict__ bfc, const float* __restrict__ Wc,
    const float* __restrict__ bc, float* __restrict__ out) {
    __shared__ float yl[1296];       // 81 positions x 16 ch, [p][ch]
    __shared__ float zl[16][41];     // after maxpool, [ch][pos<40], pad
    __shared__ float xr[416];        // conv2 out, index oc*13+t
    __shared__ float k2s[1536];
    __shared__ float fl[128];
    __shared__ float ll[10];
    int t = threadIdx.x;
    int b = blockIdx.x;
    const float* yb = y1 + (size_t)b * 1296;
    for (int i = t; i < 1296; i += 128) yl[i] = yb[i];
    for (int i = t; i < 1536; i += 128) k2s[i] = k2[i];
    __syncthreads();
    // maxpool over position pairs (drop pos 80)
    for (int i = t; i < 640; i += 128) {
        int ic = i & 15, p = i >> 4;
        zl[ic][p] = fmaxf(yl[(2 * p) * 16 + ic], yl[(2 * p + 1) * 16 + ic]);
    }
    __syncthreads();
    // conv2: 32 out-ch x 13 positions, stride 3, k=3
    for (int i = t; i < 416; i += 128) {
        int oc = i / 13, tt = i - oc * 13;
        float acc = bk2[oc];
        for (int ic = 0; ic < 16; ic++) {
            const float* kk = &k2s[(oc * 16 + ic) * 3];
            acc += zl[ic][3 * tt]     * kk[0]
                 + zl[ic][3 * tt + 1] * kk[1]
                 + zl[ic][3 * tt + 2] * kk[2];
        }
        xr[i] = acc;
    }
    __syncthreads();
    // FC 416 -> 128, one thread per output, coalesced WfcT reads
    {
        float acc = bfc[t];
        for (int i = 0; i < 416; i++) acc += xr[i] * WfcT[i * 128 + t];
        fl[t] = fmaxf(acc, 0.f);
    }
    __syncthreads();
    if (t < 10) {
        float acc = bc[t];
        for (int u = 0; u < 128; u++) acc += fl[u] * Wc[t * 128 + u];
        ll[t] = acc;
    }
    __syncthreads();
    if (t < 10) {
        float m = -1e30f;
        for (int c = 0; c < 10; c++) m = fmaxf(m, ll[c]);
        float s = 0.f;
        for (int c = 0; c < 10; c++) s += __expf(ll[c] - m);
        out[b * 10 + t] = ll[t] - m - __logf(s);
    }
}

// ---------------- launch ----------------

extern "C" void kernel_launch(void* const* d_in, const int* in_sizes, int n_in,
                              void* d_out, int out_size, void* d_ws, size_t ws_size,
                              hipStream_t stream) {
    const int*   src   = (const int*)d_in[0];
    const int*   dst   = (const int*)d_in[1];
    const float* w     = (const float*)d_in[2];
    const float* W1    = (const float*)d_in[4];
    const float* b1    = (const float*)d_in[5];
    const float* bias1 = (const float*)d_in[6];
    const float* c1s   = (const float*)d_in[7];
    const float* c1p   = (const float*)d_in[8];
    const float* c1n   = (const float*)d_in[9];
    const float* W2    = (const float*)d_in[10];
    const float* b2    = (const float*)d_in[11];
    const float* bias2 = (const float*)d_in[12];
    const float* c2s   = (const float*)d_in[13];
    const float* c2p   = (const float*)d_in[14];
    const float* c2n   = (const float*)d_in[15];
    const float* k1    = (const float*)d_in[16];
    const float* bk1   = (const float*)d_in[17];
    const float* k2    = (const float*)d_in[18];
    const float* bk2   = (const float*)d_in[19];
    const float* Wfc   = (const float*)d_in[20];
    const float* bfc   = (const float*)d_in[21];
    const float* Wc    = (const float*)d_in[22];
    const float* bc    = (const float*)d_in[23];
    const int E = in_sizes[0];
    const int NT = (E + TE - 1) / TE;

    // workspace carve (256B aligned)
    size_t off = 0;
    auto carve = [&](size_t bytes) -> char* {
        char* p = (char*)d_ws + off;
        off = (off + bytes + 255) & ~(size_t)255;
        return p;
    };
    int*   cnt    = (int*)  carve((size_t)NNODES * 4);
    int*   offs   = (int*)  carve((size_t)NNODES * 4);
    int2*  csrB   = (int2*) carve((size_t)E * 8);
    int*   H      = (int*)  carve((size_t)NT * NBUCK * 4);
    int*   T      = (int*)  carve((size_t)NBUCK * 4);
    int*   Bstart = (int*)  carve((size_t)(NBUCK + 1) * 4);
    float* spos   = (float*)carve((size_t)NNODES * 4);
    float* sneg   = (float*)carve((size_t)NNODES * 4);
    unsigned short* h1b = (unsigned short*)carve((size_t)NNODES * 32 * 2);
    float* hp     = (float*)carve((size_t)NNODES * 32 * 4);
    float* hn     = (float*)carve((size_t)NNODES * 32 * 4);
    float* y1     = (float*)carve((size_t)NNODES * 16 * 4);
    float* WfcT   = (float*)carve((size_t)128 * 416 * 4);
    unsigned short* W2sT = (unsigned short*)carve((size_t)96 * 32 * 2);
    unsigned short* k1T  = (unsigned short*)carve((size_t)64 * 16 * 2);
    (void)ws_size;

    k_hist      <<<NT, 256, 0, stream>>>(dst, H, E);
    k_colscan   <<<NBUCK / 256, 256, 0, stream>>>(H, T, NT);
    k_binscan   <<<1, 256, 0, stream>>>(T, Bstart);
    k_place     <<<NT, 256, 0, stream>>>(src, dst, w, H, Bstart, csrB, E);
    k_sortbucket<<<NBUCK, 256, 0, stream>>>(csrB, Bstart, cnt, offs);
    k_layer1    <<<NNODES / 8, 256, 0, stream>>>(cnt, offs, csrB, spos, sneg,
                                                 h1b,
                                                 W1, b1, bias1, c1s, c1p, c1n);
    k_prep      <<<17, 256, 0, stream>>>(W2, c2s, c2p, c2n, k1, W2sT, k1T);
    k_transpose <<<(128 * 416 + 255) / 256, 256, 0, stream>>>(Wfc, WfcT);
    k_agg       <<<NNODES / 8, 256, 0, stream>>>(cnt, offs, csrB, spos, sneg,
                                                 h1b, hp, hn);
    k_mlp_mfma  <<<NNODES / 256, 256, 0, stream>>>(h1b, hp, hn, W2sT, k1T,
                                                   b2, bias2, bk1, y1);
    k_head      <<<NGRAPH, 128, 0, stream>>>(y1, k2, bk2, WfcT, bfc, Wc, bc,
                                             (float*)d_out);
}

// Round 11
// 531.628 us; speedup vs baseline: 1.5600x; 1.0535x over previous
//
#include <hip/hip_runtime.h>
#include <hip/hip_bf16.h>

#define NNODES 331776            // 81 * 4096
#define NGRAPH 4096
#define NBUCK  2048              // buckets
#define BNODES 162               // nodes per bucket (2048*162 == 331776)
#define TE     16384             // edges per tile
#define CAP    2560              // max edges/bucket (lambda=1953, 13.7 sigma)

typedef __attribute__((ext_vector_type(8))) short bf8;   // 8 bf16 (4 VGPR)
typedef __attribute__((ext_vector_type(4))) float f4;    // 4 fp32 acc

static __device__ __forceinline__ short f2bf(float x) {
    return (short)__builtin_bit_cast(unsigned short, __float2bfloat16(x));
}
static __device__ __forceinline__ float bf2f(unsigned short u) {
    return __bfloat162float(__hip_bfloat16_raw{u});
}

// ---------------- deterministic bucket sort (no global atomics) ----------------

__global__ __launch_bounds__(256) void k_hist(const int* __restrict__ dst,
                                              int* __restrict__ H, int E) {
    __shared__ int h[NBUCK];
    int t = threadIdx.x, b = blockIdx.x;
    for (int i = t; i < NBUCK; i += 256) h[i] = 0;
    __syncthreads();
    int lo = b * TE, hi = min(E, lo + TE);
    for (int e = lo + t; e < hi; e += 256)
        atomicAdd(&h[dst[e] / BNODES], 1);
    __syncthreads();
    for (int i = t; i < NBUCK; i += 256) H[b * NBUCK + i] = h[i];
}

// per-bucket exclusive scan across tiles (in place); T[bin] = total
__global__ void k_colscan(int* __restrict__ H, int* __restrict__ T, int NT) {
    int bin = blockIdx.x * 256 + threadIdx.x;
    int s = 0;
    for (int t = 0; t < NT; t++) {
        int v = H[t * NBUCK + bin];
        H[t * NBUCK + bin] = s;
        s += v;
    }
    T[bin] = s;
}

// exclusive scan over the 2048 bucket totals -> Bstart[0..NBUCK]
__global__ __launch_bounds__(256) void k_binscan(const int* __restrict__ T,
                                                 int* __restrict__ Bstart) {
    __shared__ int tmp[256];
    int t = threadIdx.x;
    int base = t * 8;
    int loc[8]; int s = 0;
#pragma unroll
    for (int i = 0; i < 8; i++) { loc[i] = s; s += T[base + i]; }
    tmp[t] = s; __syncthreads();
    for (int o = 1; o < 256; o <<= 1) {
        int a = (t >= o) ? tmp[t - o] : 0;
        __syncthreads();
        tmp[t] += a;
        __syncthreads();
    }
    int excl = tmp[t] - s;
#pragma unroll
    for (int i = 0; i < 8; i++) Bstart[base + i] = excl + loc[i];
    if (t == 255) Bstart[NBUCK] = excl + s;
}

// place edges into bucket-major order; payload packs (src | dst_local<<19, esig)
// esig = sign(w)*exp(|w|) computed once here.
__global__ __launch_bounds__(256) void k_place(
    const int* __restrict__ src, const int* __restrict__ dst,
    const float* __restrict__ w,
    const int* __restrict__ H, const int* __restrict__ Bstart,
    int2* __restrict__ csrB, int E) {
    __shared__ int cur[NBUCK];
    int t = threadIdx.x, b = blockIdx.x;
    for (int i = t; i < NBUCK; i += 256)
        cur[i] = Bstart[i] + H[b * NBUCK + i];
    __syncthreads();
    int lo = b * TE, hi = min(E, lo + TE);
    for (int e = lo + t; e < hi; e += 256) {
        int d  = dst[e];
        int sx = src[e];
        float wv = w[e];
        float es = 0.f;
        if (wv > 0.f)      es = __expf(wv);
        else if (wv < 0.f) es = -__expf(-wv);
        int bin = d / BNODES;
        int dl  = d - bin * BNODES;
        int p = atomicAdd(&cur[bin], 1);        // LDS atomic; same-bin runs -> consecutive p
        int2 pk;
        pk.x = sx | (dl << 19);
        pk.y = __float_as_int(es);
        csrB[p] = pk;
    }
}

// per-bucket counting sort (in place), emits cnt[] and offs[] for free.
__global__ __launch_bounds__(256) void k_sortbucket(
    int2* __restrict__ csrB, const int* __restrict__ Bstart,
    int* __restrict__ cnt, int* __restrict__ offs) {
    __shared__ int2 pb[CAP];
    __shared__ int lcnt[BNODES];
    __shared__ int lpos[BNODES];
    int t = threadIdx.x, b = blockIdx.x;
    int lo = Bstart[b];
    int S  = Bstart[b + 1] - lo;
    if (S > CAP) S = CAP;                        // memory-safety guard (never expected)
    for (int i = t; i < BNODES; i += 256) lcnt[i] = 0;
    __syncthreads();
    for (int i = t; i < S; i += 256) {
        int2 pk = csrB[lo + i];                  // coalesced
        pb[i] = pk;
        atomicAdd(&lcnt[pk.x >> 19], 1);
    }
    __syncthreads();
    if (t == 0) {
        int s = 0;
        for (int i = 0; i < BNODES; i++) { lpos[i] = s; s += lcnt[i]; }
    }
    __syncthreads();
    int node0 = b * BNODES;
    for (int i = t; i < BNODES; i += 256) {
        cnt[node0 + i]  = lcnt[i];
        offs[node0 + i] = lo + lpos[i];
    }
    __syncthreads();
    for (int i = t; i < S; i += 256) {
        int2 pk = pb[i];
        int dl = pk.x >> 19;
        int p = atomicAdd(&lpos[dl], 1);
        int2 outv;
        outv.x = pk.x & 0x7FFFF;                 // unpacked src
        outv.y = pk.y;                           // esig
        csrB[lo + p] = outv;                     // bucket-local, L2-hot
    }
}

// ---------------- Layer 1 (h0 = deg, 1 feature -> 32), bf16 output ----------

__global__ __launch_bounds__(256) void k_layer1(
    const int* __restrict__ cnt, const int* __restrict__ offs,
    const int2* __restrict__ csr,
    float* __restrict__ spos, float* __restrict__ sneg,
    unsigned short* __restrict__ h1b,
    const float* __restrict__ W1, const float* __restrict__ b1,
    const float* __restrict__ bias1,
    const float* __restrict__ c1s, const float* __restrict__ c1p,
    const float* __restrict__ c1n) {
    int t = threadIdx.x;
    int g = t >> 5, f = t & 31;
    int d = blockIdx.x * 8 + g;
    int beg = offs[d];
    int len = cnt[d];
    float sp = 0.f, sn = 0.f, up = 0.f, un = 0.f;
    for (int j = 0; j < len; j += 32) {
        int rem = len - j;
        if (f < rem) {
            int2 sw = csr[beg + j + f];            // coalesced 8B/lane
            float es = __int_as_float(sw.y);
            float degs = (float)cnt[sw.x];          // parallel gather, L2-hot
            float ep = fmaxf(es, 0.f), en = fmaxf(-es, 0.f);
            sp += ep; sn += en; up += degs * ep; un += degs * en;
        }
    }
    for (int m = 16; m; m >>= 1) {
        sp += __shfl_xor(sp, m, 32);
        sn += __shfl_xor(sn, m, 32);
        up += __shfl_xor(up, m, 32);
        un += __shfl_xor(un, m, 32);
    }
    if (f == 0) { spos[d] = sp; sneg[d] = sn; }
    float hp = up / fmaxf(sp, 1e-20f);
    float hn = un / fmaxf(sn, 1e-20f);
    float x0 = c1s[0] * (float)len;   // deg[d] == len
    float x1 = c1p[0] * hp;
    float x2 = c1n[0] * hn;
    float v = W1[f * 3] * x0 + W1[f * 3 + 1] * x1 + W1[f * 3 + 2] * x2
            + b1[f] + bias1[f];
    v = fmaxf(v, 0.f);
    h1b[d * 32 + f] = (unsigned short)f2bf(v);      // bf16 table (gathered + MFMA A)
}

// ---------------- Layer-2 aggregation ----------------------------------------
// Half-wave per node. Per-lane ep/en pre-max (VALU 5->3 ops/edge; max moved
// off the consume path onto the DS-pipe shuffles). First batch padded to 16
// (es=0 pads are arithmetic no-ops; sx=0 pads hit the L1-hot node-0 line) so
// ~16 gathers/wave are in flight. Outputs bf16 (consumer is MFMA bf16 anyway).

__global__ __launch_bounds__(256) void k_agg(
    const int* __restrict__ cnt, const int* __restrict__ offs,
    const int2* __restrict__ csr,
    const float* __restrict__ spos, const float* __restrict__ sneg,
    const unsigned short* __restrict__ h1b,
    unsigned short* __restrict__ hpb, unsigned short* __restrict__ hnb) {
    int t = threadIdx.x;
    int g = t >> 5, f = t & 31;
    int d = blockIdx.x * 8 + g;     // NNODES % 8 == 0
    int beg = offs[d];
    int len = cnt[d];
    float ap = 0.f, an = 0.f;
    for (int j = 0; j < len; j += 32) {
        int rem = len - j;
        int sx = 0;
        float es = 0.f;
        if (f < rem) {
            int2 sw = csr[beg + j + f];            // coalesced 8B/lane
            sx = sw.x;
            es = __int_as_float(sw.y);
        }
        float ep = fmaxf(es, 0.f);                 // per-lane pre-max (amortized)
        float en = fmaxf(-es, 0.f);
        int n = rem < 32 ? rem : 32;
        // padded 16-batch: covers ~90% of chunks entirely (mean degree ~12)
        {
            float pv[16], nv[16], hv[16];
#pragma unroll
            for (int u = 0; u < 16; u++) {
                int s = __shfl(sx, u, 32);
                pv[u] = __shfl(ep, u, 32);
                nv[u] = __shfl(en, u, 32);
                hv[u] = bf2f(h1b[s * 32 + f]);     // 16 independent gathers
            }
#pragma unroll
            for (int u = 0; u < 16; u++) {
                ap = fmaf(pv[u], hv[u], ap);
                an = fmaf(nv[u], hv[u], an);
            }
        }
        for (int q = 16; q < n; q += 8) {          // overflow (padded to 8)
            float pv[8], nv[8], hv[8];
#pragma unroll
            for (int u = 0; u < 8; u++) {
                int s = __shfl(sx, q + u, 32);
                pv[u] = __shfl(ep, q + u, 32);
                nv[u] = __shfl(en, q + u, 32);
                hv[u] = bf2f(h1b[s * 32 + f]);
            }
#pragma unroll
            for (int u = 0; u < 8; u++) {
                ap = fmaf(pv[u], hv[u], ap);
                an = fmaf(nv[u], hv[u], an);
            }
        }
    }
    hpb[d * 32 + f] = (unsigned short)f2bf(ap / fmaxf(spos[d], 1e-20f));
    hnb[d * 32 + f] = (unsigned short)f2bf(an / fmaxf(sneg[d], 1e-20f));
}

// ---------------- weight prep: bf16 transposed, scales folded ---------------
// W2sT[k][n] = bf16(W2[n][k] * c_{k/32})   (96 x 32)
// k1T[k][o]  = bf16(k1[o][k])              (64 x 16)

__global__ __launch_bounds__(256) void k_prep(
    const float* __restrict__ W2, const float* __restrict__ c2s,
    const float* __restrict__ c2p, const float* __restrict__ c2n,
    const float* __restrict__ k1,
    unsigned short* __restrict__ W2sT, unsigned short* __restrict__ k1T) {
    int i = blockIdx.x * 256 + threadIdx.x;
    if (i < 96 * 32) {
        int k = i >> 5, n = i & 31;
        float sc = (k < 32) ? c2s[0] : ((k < 64) ? c2p[0] : c2n[0]);
        W2sT[i] = (unsigned short)f2bf(W2[n * 96 + k] * sc);
    } else if (i < 96 * 32 + 64 * 16) {
        int j = i - 3072;
        int k = j >> 4, o = j & 15;
        k1T[j] = (unsigned short)f2bf(k1[o * 64 + k]);
    }
}

// ---------------- Layer-2 MLP + conv1 via MFMA ------------------------------
// Per wave-group of 16 nodes:
//   GEMM1: H2(16x32) = X(16x96) . W2sT(96x32)   -> 6 mfma_f32_16x16x32_bf16
//   relu + bias, transpose C->A layout via private LDS tile (bf16)
//   GEMM2: Y(16x16)  = [h1|h2](16x64) . k1T(64x16) -> 2 mfma
// Layouts (verified): A[m=lane&15][k=quad*8+j]; B[k=quad*8+j][n=lane&15];
// C/D[row=quad*4+reg][col=lane&15].

__global__ __launch_bounds__(256) void k_mlp_mfma(
    const unsigned short* __restrict__ h1b,
    const unsigned short* __restrict__ hpb, const unsigned short* __restrict__ hnb,
    const unsigned short* __restrict__ W2sT, const unsigned short* __restrict__ k1T,
    const float* __restrict__ b2, const float* __restrict__ bias2,
    const float* __restrict__ bk1,
    float* __restrict__ y1) {
    __shared__ unsigned short h2s[4][16 * 32];     // per-wave transpose tile
    int t = threadIdx.x;
    int wv = t >> 6;
    int lane = t & 63;
    int col = lane & 15;
    int quad = lane >> 4;

    float bv0 = b2[col] + bias2[col];
    float bv1 = b2[col + 16] + bias2[col + 16];
    float bky = bk1[col];

    // B-frags: W2sT (6) + k1T (2), loop-invariant, ~32 VGPR
    bf8 BW[2][3];
#pragma unroll
    for (int nt = 0; nt < 2; nt++)
#pragma unroll
        for (int kt = 0; kt < 3; kt++) {
            bf8 b;
#pragma unroll
            for (int j = 0; j < 8; j++)
                b[j] = (short)W2sT[(kt * 32 + quad * 8 + j) * 32 + nt * 16 + col];
            BW[nt][kt] = b;
        }
    bf8 BK[2];
#pragma unroll
    for (int kt = 0; kt < 2; kt++) {
        bf8 b;
#pragma unroll
        for (int j = 0; j < 8; j++)
            b[j] = (short)k1T[(kt * 32 + quad * 8 + j) * 16 + col];
        BK[kt] = b;
    }
    unsigned short* myT = h2s[wv];

#pragma unroll 1
    for (int g = 0; g < 4; g++) {
        int nbase = blockIdx.x * 256 + wv * 64 + g * 16;
        int node = nbase + col;                     // A-operand row m = col
        // A-frags: all direct bf16 16B loads
        bf8 a0 = *(const bf8*)(h1b + (size_t)node * 32 + quad * 8);
        bf8 a1 = *(const bf8*)(hpb + (size_t)node * 32 + quad * 8);
        bf8 a2 = *(const bf8*)(hnb + (size_t)node * 32 + quad * 8);

        f4 acc0 = {bv0, bv0, bv0, bv0};
        f4 acc1 = {bv1, bv1, bv1, bv1};
        acc0 = __builtin_amdgcn_mfma_f32_16x16x32_bf16(a0, BW[0][0], acc0, 0, 0, 0);
        acc0 = __builtin_amdgcn_mfma_f32_16x16x32_bf16(a1, BW[0][1], acc0, 0, 0, 0);
        acc0 = __builtin_amdgcn_mfma_f32_16x16x32_bf16(a2, BW[0][2], acc0, 0, 0, 0);
        acc1 = __builtin_amdgcn_mfma_f32_16x16x32_bf16(a0, BW[1][0], acc1, 0, 0, 0);
        acc1 = __builtin_amdgcn_mfma_f32_16x16x32_bf16(a1, BW[1][1], acc1, 0, 0, 0);
        acc1 = __builtin_amdgcn_mfma_f32_16x16x32_bf16(a2, BW[1][2], acc1, 0, 0, 0);

        // relu -> bf16 -> LDS (C layout: row=quad*4+i, col)
#pragma unroll
        for (int i = 0; i < 4; i++) {
            int r = quad * 4 + i;
            myT[r * 32 + col]      = (unsigned short)f2bf(fmaxf(acc0[i], 0.f));
            myT[r * 32 + col + 16] = (unsigned short)f2bf(fmaxf(acc1[i], 0.f));
        }
        // read back in A layout (same wave -> compiler inserts lgkm wait)
        bf8 ah2 = *(const bf8*)(myT + col * 32 + quad * 8);

        f4 accy = {bky, bky, bky, bky};
        accy = __builtin_amdgcn_mfma_f32_16x16x32_bf16(a0,  BK[0], accy, 0, 0, 0);
        accy = __builtin_amdgcn_mfma_f32_16x16x32_bf16(ah2, BK[1], accy, 0, 0, 0);
#pragma unroll
        for (int i = 0; i < 4; i++)
            y1[(size_t)(nbase + quad * 4 + i) * 16 + col] = accy[i];
    }
}

// ---------------- Wfc transpose (for coalesced FC reads) ----------------

__global__ void k_transpose(const float* __restrict__ Wfc, float* __restrict__ WfcT) {
    int i = blockIdx.x * 256 + threadIdx.x;
    if (i < 128 * 416) {
        int u = i / 416, c = i - u * 416;
        WfcT[c * 128 + u] = Wfc[i];
    }
}

// ---------------- Head: maxpool -> conv2 -> FC -> classifier -> log_softmax ----

__global__ __launch_bounds__(128) void k_head(
    const float* __restrict__ y1, const float* __restrict__ k2,
    const float* __restrict__ bk2, const float* __restrict__ WfcT,
    const float* __restrict__ bfc, const float* __restrict__ Wc,
    const float* __restrict__ bc, float* __restrict__ out) {
    __shared__ float yl[1296];       // 81 positions x 16 ch, [p][ch]
    __shared__ float zl[16][41];     // after maxpool, [ch][pos<40], pad
    __shared__ float xr[416];        // conv2 out, index oc*13+t
    __shared__ float k2s[1536];
    __shared__ float fl[128];
    __shared__ float ll[10];
    int t = threadIdx.x;
    int b = blockIdx.x;
    const float* yb = y1 + (size_t)b * 1296;
    for (int i = t; i < 1296; i += 128) yl[i] = yb[i];
    for (int i = t; i < 1536; i += 128) k2s[i] = k2[i];
    __syncthreads();
    // maxpool over position pairs (drop pos 80)
    for (int i = t; i < 640; i += 128) {
        int ic = i & 15, p = i >> 4;
        zl[ic][p] = fmaxf(yl[(2 * p) * 16 + ic], yl[(2 * p + 1) * 16 + ic]);
    }
    __syncthreads();
    // conv2: 32 out-ch x 13 positions, stride 3, k=3
    for (int i = t; i < 416; i += 128) {
        int oc = i / 13, tt = i - oc * 13;
        float acc = bk2[oc];
        for (int ic = 0; ic < 16; ic++) {
            const float* kk = &k2s[(oc * 16 + ic) * 3];
            acc += zl[ic][3 * tt]     * kk[0]
                 + zl[ic][3 * tt + 1] * kk[1]
                 + zl[ic][3 * tt + 2] * kk[2];
        }
        xr[i] = acc;
    }
    __syncthreads();
    // FC 416 -> 128, one thread per output, coalesced WfcT reads
    {
        float acc = bfc[t];
        for (int i = 0; i < 416; i++) acc += xr[i] * WfcT[i * 128 + t];
        fl[t] = fmaxf(acc, 0.f);
    }
    __syncthreads();
    if (t < 10) {
        float acc = bc[t];
        for (int u = 0; u < 128; u++) acc += fl[u] * Wc[t * 128 + u];
        ll[t] = acc;
    }
    __syncthreads();
    if (t < 10) {
        float m = -1e30f;
        for (int c = 0; c < 10; c++) m = fmaxf(m, ll[c]);
        float s = 0.f;
        for (int c = 0; c < 10; c++) s += __expf(ll[c] - m);
        out[b * 10 + t] = ll[t] - m - __logf(s);
    }
}

// ---------------- launch ----------------

extern "C" void kernel_launch(void* const* d_in, const int* in_sizes, int n_in,
                              void* d_out, int out_size, void* d_ws, size_t ws_size,
                              hipStream_t stream) {
    const int*   src   = (const int*)d_in[0];
    const int*   dst   = (const int*)d_in[1];
    const float* w     = (const float*)d_in[2];
    const float* W1    = (const float*)d_in[4];
    const float* b1    = (const float*)d_in[5];
    const float* bias1 = (const float*)d_in[6];
    const float* c1s   = (const float*)d_in[7];
    const float* c1p   = (const float*)d_in[8];
    const float* c1n   = (const float*)d_in[9];
    const float* W2    = (const float*)d_in[10];
    const float* b2    = (const float*)d_in[11];
    const float* bias2 = (const float*)d_in[12];
    const float* c2s   = (const float*)d_in[13];
    const float* c2p   = (const float*)d_in[14];
    const float* c2n   = (const float*)d_in[15];
    const float* k1    = (const float*)d_in[16];
    const float* bk1   = (const float*)d_in[17];
    const float* k2    = (const float*)d_in[18];
    const float* bk2   = (const float*)d_in[19];
    const float* Wfc   = (const float*)d_in[20];
    const float* bfc   = (const float*)d_in[21];
    const float* Wc    = (const float*)d_in[22];
    const float* bc    = (const float*)d_in[23];
    const int E = in_sizes[0];
    const int NT = (E + TE - 1) / TE;

    // workspace carve (256B aligned)
    size_t off = 0;
    auto carve = [&](size_t bytes) -> char* {
        char* p = (char*)d_ws + off;
        off = (off + bytes + 255) & ~(size_t)255;
        return p;
    };
    int*   cnt    = (int*)  carve((size_t)NNODES * 4);
    int*   offs   = (int*)  carve((size_t)NNODES * 4);
    int2*  csrB   = (int2*) carve((size_t)E * 8);
    int*   H      = (int*)  carve((size_t)NT * NBUCK * 4);
    int*   T      = (int*)  carve((size_t)NBUCK * 4);
    int*   Bstart = (int*)  carve((size_t)(NBUCK + 1) * 4);
    float* spos   = (float*)carve((size_t)NNODES * 4);
    float* sneg   = (float*)carve((size_t)NNODES * 4);
    unsigned short* h1b = (unsigned short*)carve((size_t)NNODES * 32 * 2);
    unsigned short* hpb = (unsigned short*)carve((size_t)NNODES * 32 * 2);
    unsigned short* hnb = (unsigned short*)carve((size_t)NNODES * 32 * 2);
    float* y1     = (float*)carve((size_t)NNODES * 16 * 4);
    float* WfcT   = (float*)carve((size_t)128 * 416 * 4);
    unsigned short* W2sT = (unsigned short*)carve((size_t)96 * 32 * 2);
    unsigned short* k1T  = (unsigned short*)carve((size_t)64 * 16 * 2);
    (void)ws_size;

    k_hist      <<<NT, 256, 0, stream>>>(dst, H, E);
    k_colscan   <<<NBUCK / 256, 256, 0, stream>>>(H, T, NT);
    k_binscan   <<<1, 256, 0, stream>>>(T, Bstart);
    k_place     <<<NT, 256, 0, stream>>>(src, dst, w, H, Bstart, csrB, E);
    k_sortbucket<<<NBUCK, 256, 0, stream>>>(csrB, Bstart, cnt, offs);
    k_layer1    <<<NNODES / 8, 256, 0, stream>>>(cnt, offs, csrB, spos, sneg,
                                                 h1b,
                                                 W1, b1, bias1, c1s, c1p, c1n);
    k_prep      <<<17, 256, 0, stream>>>(W2, c2s, c2p, c2n, k1, W2sT, k1T);
    k_transpose <<<(128 * 416 + 255) / 256, 256, 0, stream>>>(Wfc, WfcT);
    k_agg       <<<NNODES / 8, 256, 0, stream>>>(cnt, offs, csrB, spos, sneg,
                                                 h1b, hpb, hnb);
    k_mlp_mfma  <<<NNODES / 256, 256, 0, stream>>>(h1b, hpb, hnb, W2sT, k1T,
                                                   b2, bias2, bk1, y1);
    k_head      <<<NGRAPH, 128, 0, stream>>>(y1, k2, bk2, WfcT, bfc, Wc, bc,
                                             (float*)d_out);
}

// Round 12
// 531.021 us; speedup vs baseline: 1.5618x; 1.0011x over previous
//
#include <hip/hip_runtime.h>
#include <hip/hip_bf16.h>

#define NNODES 331776            // 81 * 4096
#define NGRAPH 4096
#define NBUCK  2048              // buckets
#define BNODES 162               // nodes per bucket (2048*162 == 331776)
#define TE     16384             // edges per tile
#define CAP    2560              // max edges/bucket (lambda=1953, 13.7 sigma)

typedef __attribute__((ext_vector_type(8))) short bf8;   // 8 bf16 (4 VGPR)
typedef __attribute__((ext_vector_type(4))) float f4;    // 4 fp32 acc

static __device__ __forceinline__ short f2bf(float x) {
    return (short)__builtin_bit_cast(unsigned short, __float2bfloat16(x));
}
static __device__ __forceinline__ float bf2f(unsigned short u) {
    return __bfloat162float(__hip_bfloat16_raw{u});
}

// ---------------- deterministic bucket sort (no global atomics) ----------------

__global__ __launch_bounds__(256) void k_hist(const int* __restrict__ dst,
                                              int* __restrict__ H, int E) {
    __shared__ int h[NBUCK];
    int t = threadIdx.x, b = blockIdx.x;
    for (int i = t; i < NBUCK; i += 256) h[i] = 0;
    __syncthreads();
    int lo = b * TE, hi = min(E, lo + TE);
    for (int e = lo + t; e < hi; e += 256)
        atomicAdd(&h[dst[e] / BNODES], 1);
    __syncthreads();
    for (int i = t; i < NBUCK; i += 256) H[b * NBUCK + i] = h[i];
}

// per-bucket exclusive scan across tiles (in place); T[bin] = total
__global__ void k_colscan(int* __restrict__ H, int* __restrict__ T, int NT) {
    int bin = blockIdx.x * 256 + threadIdx.x;
    int s = 0;
    for (int t = 0; t < NT; t++) {
        int v = H[t * NBUCK + bin];
        H[t * NBUCK + bin] = s;
        s += v;
    }
    T[bin] = s;
}

// exclusive scan over the 2048 bucket totals -> Bstart[0..NBUCK]
__global__ __launch_bounds__(256) void k_binscan(const int* __restrict__ T,
                                                 int* __restrict__ Bstart) {
    __shared__ int tmp[256];
    int t = threadIdx.x;
    int base = t * 8;
    int loc[8]; int s = 0;
#pragma unroll
    for (int i = 0; i < 8; i++) { loc[i] = s; s += T[base + i]; }
    tmp[t] = s; __syncthreads();
    for (int o = 1; o < 256; o <<= 1) {
        int a = (t >= o) ? tmp[t - o] : 0;
        __syncthreads();
        tmp[t] += a;
        __syncthreads();
    }
    int excl = tmp[t] - s;
#pragma unroll
    for (int i = 0; i < 8; i++) Bstart[base + i] = excl + loc[i];
    if (t == 255) Bstart[NBUCK] = excl + s;
}

// place edges into bucket-major order; payload packs (src | dst_local<<19, esig)
// esig = sign(w)*exp(|w|) computed once here (sign consumed by k_sortbucket).
__global__ __launch_bounds__(256) void k_place(
    const int* __restrict__ src, const int* __restrict__ dst,
    const float* __restrict__ w,
    const int* __restrict__ H, const int* __restrict__ Bstart,
    int2* __restrict__ csrB, int E) {
    __shared__ int cur[NBUCK];
    int t = threadIdx.x, b = blockIdx.x;
    for (int i = t; i < NBUCK; i += 256)
        cur[i] = Bstart[i] + H[b * NBUCK + i];
    __syncthreads();
    int lo = b * TE, hi = min(E, lo + TE);
    for (int e = lo + t; e < hi; e += 256) {
        int d  = dst[e];
        int sx = src[e];
        float wv = w[e];
        float es = 0.f;
        if (wv > 0.f)      es = __expf(wv);
        else if (wv < 0.f) es = -__expf(-wv);
        int bin = d / BNODES;
        int dl  = d - bin * BNODES;
        int p = atomicAdd(&cur[bin], 1);        // LDS atomic; same-bin runs -> consecutive p
        int2 pk;
        pk.x = sx | (dl << 19);
        pk.y = __float_as_int(es);
        csrB[p] = pk;
    }
}

// per-bucket counting sort (in place), key = dst_local*2 + sign:
// each node's edges land [positives | negatives], payload stores |es|.
// Emits cnt[] (total), cntp[] (positive count), offs[] (start).
__global__ __launch_bounds__(256) void k_sortbucket(
    int2* __restrict__ csrB, const int* __restrict__ Bstart,
    int* __restrict__ cnt, int* __restrict__ cntp, int* __restrict__ offs) {
    __shared__ int2 pb[CAP];
    __shared__ int lcnt[BNODES * 2];
    __shared__ int lpos[BNODES * 2];
    int t = threadIdx.x, b = blockIdx.x;
    int lo = Bstart[b];
    int S  = Bstart[b + 1] - lo;
    if (S > CAP) S = CAP;                        // memory-safety guard (never expected)
    for (int i = t; i < BNODES * 2; i += 256) lcnt[i] = 0;
    __syncthreads();
    for (int i = t; i < S; i += 256) {
        int2 pk = csrB[lo + i];                  // coalesced
        pb[i] = pk;
        int key = ((pk.x >> 19) << 1) | ((unsigned)pk.y >> 31);
        atomicAdd(&lcnt[key], 1);
    }
    __syncthreads();
    if (t == 0) {
        int s = 0;
        for (int i = 0; i < BNODES * 2; i++) { lpos[i] = s; s += lcnt[i]; }
    }
    __syncthreads();
    int node0 = b * BNODES;
    for (int i = t; i < BNODES; i += 256) {
        cnt[node0 + i]  = lcnt[2 * i] + lcnt[2 * i + 1];
        cntp[node0 + i] = lcnt[2 * i];
        offs[node0 + i] = lo + lpos[2 * i];
    }
    __syncthreads();
    for (int i = t; i < S; i += 256) {
        int2 pk = pb[i];
        int key = ((pk.x >> 19) << 1) | ((unsigned)pk.y >> 31);
        int p = atomicAdd(&lpos[key], 1);
        int2 outv;
        outv.x = pk.x & 0x7FFFF;                 // unpacked src
        outv.y = pk.y & 0x7FFFFFFF;              // |es| (sign now positional)
        csrB[lo + p] = outv;                     // bucket-local, L2-hot
    }
}

// ---------------- Layer 1 (h0 = deg, 1 feature -> 32), bf16 output ----------
// Magnitude payload; sign from position (j+f < np).

__global__ __launch_bounds__(256) void k_layer1(
    const int* __restrict__ cnt, const int* __restrict__ cntp,
    const int* __restrict__ offs, const int2* __restrict__ csr,
    float* __restrict__ spos, float* __restrict__ sneg,
    unsigned short* __restrict__ h1b,
    const float* __restrict__ W1, const float* __restrict__ b1,
    const float* __restrict__ bias1,
    const float* __restrict__ c1s, const float* __restrict__ c1p,
    const float* __restrict__ c1n) {
    int t = threadIdx.x;
    int g = t >> 5, f = t & 31;
    int d = blockIdx.x * 8 + g;
    int beg = offs[d];
    int len = cnt[d];
    int np  = cntp[d];
    float sp = 0.f, sn = 0.f, up = 0.f, un = 0.f;
    for (int j = 0; j < len; j += 32) {
        int rem = len - j;
        if (f < rem) {
            int2 sw = csr[beg + j + f];            // coalesced 8B/lane
            float es = __int_as_float(sw.y);        // |es|
            float degs = (float)cnt[sw.x];          // parallel gather, L2-hot
            float ep = (j + f < np) ? es : 0.f;
            float en = es - ep;
            sp += ep; sn += en;
            up = fmaf(degs, ep, up); un = fmaf(degs, en, un);
        }
    }
    for (int m = 16; m; m >>= 1) {
        sp += __shfl_xor(sp, m, 32);
        sn += __shfl_xor(sn, m, 32);
        up += __shfl_xor(up, m, 32);
        un += __shfl_xor(un, m, 32);
    }
    if (f == 0) { spos[d] = sp; sneg[d] = sn; }
    float hp = up / fmaxf(sp, 1e-20f);
    float hn = un / fmaxf(sn, 1e-20f);
    float x0 = c1s[0] * (float)len;   // deg[d] == len
    float x1 = c1p[0] * hp;
    float x2 = c1n[0] * hn;
    float v = W1[f * 3] * x0 + W1[f * 3 + 1] * x1 + W1[f * 3 + 2] * x2
            + b1[f] + bias1[f];
    v = fmaxf(v, 0.f);
    h1b[d * 32 + f] = (unsigned short)f2bf(v);      // bf16 table (gathered + MFMA A)
}

// ---------------- Layer-2 aggregation ----------------------------------------
// Half-wave per node; sign-partitioned ranges: 2 shuffles + 1 fma + 1 cvt per
// edge, zero sign logic (pads get e=0 via the range guard; sx=0 pads hit the
// L1-hot node-0 line). 8-deep gather batches keep loads in flight.

static __device__ __forceinline__ float range_accum(
    const int2* __restrict__ csr, const unsigned short* __restrict__ h1b,
    int rbeg, int count, int f) {
    float a = 0.f;
    for (int j = 0; j < count; j += 32) {
        int rem = count - j;
        int sx = 0;
        float e = 0.f;
        if (f < rem) {
            int2 pk = csr[rbeg + j + f];           // coalesced 8B/lane
            sx = pk.x;
            e = __int_as_float(pk.y);              // |es|
        }
        int n = rem < 32 ? rem : 32;
        for (int q = 0; q < n; q += 8) {
            float ev[8], hv[8];
#pragma unroll
            for (int u = 0; u < 8; u++) {
                int s = __shfl(sx, q + u, 32);
                ev[u] = __shfl(e, q + u, 32);
                hv[u] = bf2f(h1b[s * 32 + f]);     // 8 independent gathers
            }
#pragma unroll
            for (int u = 0; u < 8; u++) a = fmaf(ev[u], hv[u], a);
        }
    }
    return a;
}

__global__ __launch_bounds__(256) void k_agg(
    const int* __restrict__ cnt, const int* __restrict__ cntp,
    const int* __restrict__ offs, const int2* __restrict__ csr,
    const float* __restrict__ spos, const float* __restrict__ sneg,
    const unsigned short* __restrict__ h1b,
    unsigned short* __restrict__ hpb, unsigned short* __restrict__ hnb) {
    int t = threadIdx.x;
    int g = t >> 5, f = t & 31;
    int d = blockIdx.x * 8 + g;     // NNODES % 8 == 0
    int beg = offs[d];
    int len = cnt[d];
    int np  = cntp[d];
    float ap = range_accum(csr, h1b, beg, np, f);
    float an = range_accum(csr, h1b, beg + np, len - np, f);
    hpb[d * 32 + f] = (unsigned short)f2bf(ap / fmaxf(spos[d], 1e-20f));
    hnb[d * 32 + f] = (unsigned short)f2bf(an / fmaxf(sneg[d], 1e-20f));
}

// ---------------- weight prep: bf16 transposed, scales folded ---------------
// W2sT[k][n] = bf16(W2[n][k] * c_{k/32})   (96 x 32)
// k1T[k][o]  = bf16(k1[o][k])              (64 x 16)

__global__ __launch_bounds__(256) void k_prep(
    const float* __restrict__ W2, const float* __restrict__ c2s,
    const float* __restrict__ c2p, const float* __restrict__ c2n,
    const float* __restrict__ k1,
    unsigned short* __restrict__ W2sT, unsigned short* __restrict__ k1T) {
    int i = blockIdx.x * 256 + threadIdx.x;
    if (i < 96 * 32) {
        int k = i >> 5, n = i & 31;
        float sc = (k < 32) ? c2s[0] : ((k < 64) ? c2p[0] : c2n[0]);
        W2sT[i] = (unsigned short)f2bf(W2[n * 96 + k] * sc);
    } else if (i < 96 * 32 + 64 * 16) {
        int j = i - 3072;
        int k = j >> 4, o = j & 15;
        k1T[j] = (unsigned short)f2bf(k1[o * 64 + k]);
    }
}

// ---------------- Layer-2 MLP + conv1 via MFMA ------------------------------
// Per wave-group of 16 nodes:
//   GEMM1: H2(16x32) = X(16x96) . W2sT(96x32)   -> 6 mfma_f32_16x16x32_bf16
//   relu + bias, transpose C->A layout via private LDS tile (bf16)
//   GEMM2: Y(16x16)  = [h1|h2](16x64) . k1T(64x16) -> 2 mfma
// Layouts (verified): A[m=lane&15][k=quad*8+j]; B[k=quad*8+j][n=lane&15];
// C/D[row=quad*4+reg][col=lane&15].

__global__ __launch_bounds__(256) void k_mlp_mfma(
    const unsigned short* __restrict__ h1b,
    const unsigned short* __restrict__ hpb, const unsigned short* __restrict__ hnb,
    const unsigned short* __restrict__ W2sT, const unsigned short* __restrict__ k1T,
    const float* __restrict__ b2, const float* __restrict__ bias2,
    const float* __restrict__ bk1,
    float* __restrict__ y1) {
    __shared__ unsigned short h2s[4][16 * 32];     // per-wave transpose tile
    int t = threadIdx.x;
    int wv = t >> 6;
    int lane = t & 63;
    int col = lane & 15;
    int quad = lane >> 4;

    float bv0 = b2[col] + bias2[col];
    float bv1 = b2[col + 16] + bias2[col + 16];
    float bky = bk1[col];

    // B-frags: W2sT (6) + k1T (2), loop-invariant, ~32 VGPR
    bf8 BW[2][3];
#pragma unroll
    for (int nt = 0; nt < 2; nt++)
#pragma unroll
        for (int kt = 0; kt < 3; kt++) {
            bf8 b;
#pragma unroll
            for (int j = 0; j < 8; j++)
                b[j] = (short)W2sT[(kt * 32 + quad * 8 + j) * 32 + nt * 16 + col];
            BW[nt][kt] = b;
        }
    bf8 BK[2];
#pragma unroll
    for (int kt = 0; kt < 2; kt++) {
        bf8 b;
#pragma unroll
        for (int j = 0; j < 8; j++)
            b[j] = (short)k1T[(kt * 32 + quad * 8 + j) * 16 + col];
        BK[kt] = b;
    }
    unsigned short* myT = h2s[wv];

#pragma unroll 1
    for (int g = 0; g < 4; g++) {
        int nbase = blockIdx.x * 256 + wv * 64 + g * 16;
        int node = nbase + col;                     // A-operand row m = col
        // A-frags: all direct bf16 16B loads
        bf8 a0 = *(const bf8*)(h1b + (size_t)node * 32 + quad * 8);
        bf8 a1 = *(const bf8*)(hpb + (size_t)node * 32 + quad * 8);
        bf8 a2 = *(const bf8*)(hnb + (size_t)node * 32 + quad * 8);

        f4 acc0 = {bv0, bv0, bv0, bv0};
        f4 acc1 = {bv1, bv1, bv1, bv1};
        acc0 = __builtin_amdgcn_mfma_f32_16x16x32_bf16(a0, BW[0][0], acc0, 0, 0, 0);
        acc0 = __builtin_amdgcn_mfma_f32_16x16x32_bf16(a1, BW[0][1], acc0, 0, 0, 0);
        acc0 = __builtin_amdgcn_mfma_f32_16x16x32_bf16(a2, BW[0][2], acc0, 0, 0, 0);
        acc1 = __builtin_amdgcn_mfma_f32_16x16x32_bf16(a0, BW[1][0], acc1, 0, 0, 0);
        acc1 = __builtin_amdgcn_mfma_f32_16x16x32_bf16(a1, BW[1][1], acc1, 0, 0, 0);
        acc1 = __builtin_amdgcn_mfma_f32_16x16x32_bf16(a2, BW[1][2], acc1, 0, 0, 0);

        // relu -> bf16 -> LDS (C layout: row=quad*4+i, col)
#pragma unroll
        for (int i = 0; i < 4; i++) {
            int r = quad * 4 + i;
            myT[r * 32 + col]      = (unsigned short)f2bf(fmaxf(acc0[i], 0.f));
            myT[r * 32 + col + 16] = (unsigned short)f2bf(fmaxf(acc1[i], 0.f));
        }
        // read back in A layout (same wave -> compiler inserts lgkm wait)
        bf8 ah2 = *(const bf8*)(myT + col * 32 + quad * 8);

        f4 accy = {bky, bky, bky, bky};
        accy = __builtin_amdgcn_mfma_f32_16x16x32_bf16(a0,  BK[0], accy, 0, 0, 0);
        accy = __builtin_amdgcn_mfma_f32_16x16x32_bf16(ah2, BK[1], accy, 0, 0, 0);
#pragma unroll
        for (int i = 0; i < 4; i++)
            y1[(size_t)(nbase + quad * 4 + i) * 16 + col] = accy[i];
    }
}

// ---------------- Wfc transpose (for coalesced FC reads) ----------------

__global__ void k_transpose(const float* __restrict__ Wfc, float* __restrict__ WfcT) {
    int i = blockIdx.x * 256 + threadIdx.x;
    if (i < 128 * 416) {
        int u = i / 416, c = i - u * 416;
        WfcT[c * 128 + u] = Wfc[i];
    }
}

// ---------------- Head: maxpool -> conv2 -> FC -> classifier -> log_softmax ----

__global__ __launch_bounds__(128) void k_head(
    const float* __restrict__ y1, const float* __restrict__ k2,
    const float* __restrict__ bk2, const float* __restrict__ WfcT,
    const float* __restrict__ bfc, const float* __restrict__ Wc,
    const float* __restrict__ bc, float* __restrict__ out) {
    __shared__ float yl[1296];       // 81 positions x 16 ch, [p][ch]
    __shared__ float zl[16][41];     // after maxpool, [ch][pos<40], pad
    __shared__ float xr[416];        // conv2 out, index oc*13+t
    __shared__ float k2s[1536];
    __shared__ float fl[128];
    __shared__ float ll[10];
    int t = threadIdx.x;
    int b = blockIdx.x;
    const float* yb = y1 + (size_t)b * 1296;
    for (int i = t; i < 1296; i += 128) yl[i] = yb[i];
    for (int i = t; i < 1536; i += 128) k2s[i] = k2[i];
    __syncthreads();
    // maxpool over position pairs (drop pos 80)
    for (int i = t; i < 640; i += 128) {
        int ic = i & 15, p = i >> 4;
        zl[ic][p] = fmaxf(yl[(2 * p) * 16 + ic], yl[(2 * p + 1) * 16 + ic]);
    }
    __syncthreads();
    // conv2: 32 out-ch x 13 positions, stride 3, k=3
    for (int i = t; i < 416; i += 128) {
        int oc = i / 13, tt = i - oc * 13;
        float acc = bk2[oc];
        for (int ic = 0; ic < 16; ic++) {
            const float* kk = &k2s[(oc * 16 + ic) * 3];
            acc += zl[ic][3 * tt]     * kk[0]
                 + zl[ic][3 * tt + 1] * kk[1]
                 + zl[ic][3 * tt + 2] * kk[2];
        }
        xr[i] = acc;
    }
    __syncthreads();
    // FC 416 -> 128, one thread per output, coalesced WfcT reads
    {
        float acc = bfc[t];
        for (int i = 0; i < 416; i++) acc += xr[i] * WfcT[i * 128 + t];
        fl[t] = fmaxf(acc, 0.f);
    }
    __syncthreads();
    if (t < 10) {
        float acc = bc[t];
        for (int u = 0; u < 128; u++) acc += fl[u] * Wc[t * 128 + u];
        ll[t] = acc;
    }
    __syncthreads();
    if (t < 10) {
        float m = -1e30f;
        for (int c = 0; c < 10; c++) m = fmaxf(m, ll[c]);
        float s = 0.f;
        for (int c = 0; c < 10; c++) s += __expf(ll[c] - m);
        out[b * 10 + t] = ll[t] - m - __logf(s);
    }
}

// ---------------- launch ----------------

extern "C" void kernel_launch(void* const* d_in, const int* in_sizes, int n_in,
                              void* d_out, int out_size, void* d_ws, size_t ws_size,
                              hipStream_t stream) {
    const int*   src   = (const int*)d_in[0];
    const int*   dst   = (const int*)d_in[1];
    const float* w     = (const float*)d_in[2];
    const float* W1    = (const float*)d_in[4];
    const float* b1    = (const float*)d_in[5];
    const float* bias1 = (const float*)d_in[6];
    const float* c1s   = (const float*)d_in[7];
    const float* c1p   = (const float*)d_in[8];
    const float* c1n   = (const float*)d_in[9];
    const float* W2    = (const float*)d_in[10];
    const float* b2    = (const float*)d_in[11];
    const float* bias2 = (const float*)d_in[12];
    const float* c2s   = (const float*)d_in[13];
    const float* c2p   = (const float*)d_in[14];
    const float* c2n   = (const float*)d_in[15];
    const float* k1    = (const float*)d_in[16];
    const float* bk1   = (const float*)d_in[17];
    const float* k2    = (const float*)d_in[18];
    const float* bk2   = (const float*)d_in[19];
    const float* Wfc   = (const float*)d_in[20];
    const float* bfc   = (const float*)d_in[21];
    const float* Wc    = (const float*)d_in[22];
    const float* bc    = (const float*)d_in[23];
    const int E = in_sizes[0];
    const int NT = (E + TE - 1) / TE;

    // workspace carve (256B aligned)
    size_t off = 0;
    auto carve = [&](size_t bytes) -> char* {
        char* p = (char*)d_ws + off;
        off = (off + bytes + 255) & ~(size_t)255;
        return p;
    };
    int*   cnt    = (int*)  carve((size_t)NNODES * 4);
    int*   cntp   = (int*)  carve((size_t)NNODES * 4);
    int*   offs   = (int*)  carve((size_t)NNODES * 4);
    int2*  csrB   = (int2*) carve((size_t)E * 8);
    int*   H      = (int*)  carve((size_t)NT * NBUCK * 4);
    int*   T      = (int*)  carve((size_t)NBUCK * 4);
    int*   Bstart = (int*)  carve((size_t)(NBUCK + 1) * 4);
    float* spos   = (float*)carve((size_t)NNODES * 4);
    float* sneg   = (float*)carve((size_t)NNODES * 4);
    unsigned short* h1b = (unsigned short*)carve((size_t)NNODES * 32 * 2);
    unsigned short* hpb = (unsigned short*)carve((size_t)NNODES * 32 * 2);
    unsigned short* hnb = (unsigned short*)carve((size_t)NNODES * 32 * 2);
    float* y1     = (float*)carve((size_t)NNODES * 16 * 4);
    float* WfcT   = (float*)carve((size_t)128 * 416 * 4);
    unsigned short* W2sT = (unsigned short*)carve((size_t)96 * 32 * 2);
    unsigned short* k1T  = (unsigned short*)carve((size_t)64 * 16 * 2);
    (void)ws_size;

    k_hist      <<<NT, 256, 0, stream>>>(dst, H, E);
    k_colscan   <<<NBUCK / 256, 256, 0, stream>>>(H, T, NT);
    k_binscan   <<<1, 256, 0, stream>>>(T, Bstart);
    k_place     <<<NT, 256, 0, stream>>>(src, dst, w, H, Bstart, csrB, E);
    k_sortbucket<<<NBUCK, 256, 0, stream>>>(csrB, Bstart, cnt, cntp, offs);
    k_layer1    <<<NNODES / 8, 256, 0, stream>>>(cnt, cntp, offs, csrB,
                                                 spos, sneg, h1b,
                                                 W1, b1, bias1, c1s, c1p, c1n);
    k_prep      <<<17, 256, 0, stream>>>(W2, c2s, c2p, c2n, k1, W2sT, k1T);
    k_transpose <<<(128 * 416 + 255) / 256, 256, 0, stream>>>(Wfc, WfcT);
    k_agg       <<<NNODES / 8, 256, 0, stream>>>(cnt, cntp, offs, csrB,
                                                 spos, sneg, h1b, hpb, hnb);
    k_mlp_mfma  <<<NNODES / 256, 256, 0, stream>>>(h1b, hpb, hnb, W2sT, k1T,
                                                   b2, bias2, bk1, y1);
    k_head      <<<NGRAPH, 128, 0, stream>>>(y1, k2, bk2, WfcT, bfc, Wc, bc,
                                             (float*)d_out);
}